// Round 2
// baseline (2512.250 us; speedup 1.0000x reference)
//
#include <hip/hip_runtime.h>
#include <hip/hip_bf16.h>
#include <math.h>

// Problem constants (B=1)
#define SEQ   2048
#define HID   1024
#define NH    16
#define HD    64
#define WIN   128
#define GSTR  64

// C[M,N] = A[M,K] @ B[N,K]^T   (all fp32), fp32 accumulate.
// 64x64 tile, BK=16, 256 threads, 4x4 outputs per thread.
__global__ __launch_bounds__(256) void gemm_abt(const float* __restrict__ A,
                                                const float* __restrict__ B,
                                                float* __restrict__ C,
                                                int M, int N, int K) {
    __shared__ float As[16][64];
    __shared__ float Bs[16][64];
    const int tx = threadIdx.x & 15;
    const int ty = threadIdx.x >> 4;
    const int bm = blockIdx.y * 64;
    const int bn = blockIdx.x * 64;

    float acc[4][4] = {};

    for (int k0 = 0; k0 < K; k0 += 16) {
        for (int t = threadIdx.x; t < 64 * 16; t += 256) {
            int m = t >> 4, kk = t & 15;
            As[kk][m] = A[(size_t)(bm + m) * K + k0 + kk];
        }
        for (int t = threadIdx.x; t < 64 * 16; t += 256) {
            int n = t >> 4, kk = t & 15;
            Bs[kk][n] = B[(size_t)(bn + n) * K + k0 + kk];
        }
        __syncthreads();
        #pragma unroll
        for (int kk = 0; kk < 16; ++kk) {
            float a[4], b[4];
            #pragma unroll
            for (int i = 0; i < 4; ++i) a[i] = As[kk][ty * 4 + i];
            #pragma unroll
            for (int j = 0; j < 4; ++j) b[j] = Bs[kk][tx * 4 + j];
            #pragma unroll
            for (int i = 0; i < 4; ++i)
                #pragma unroll
                for (int j = 0; j < 4; ++j)
                    acc[i][j] += a[i] * b[j];
        }
        __syncthreads();
    }
    #pragma unroll
    for (int i = 0; i < 4; ++i)
        #pragma unroll
        for (int j = 0; j < 4; ++j)
            C[(size_t)(bm + ty * 4 + i) * N + bn + tx * 4 + j] = acc[i][j];
}

// One workgroup per (query i, head h). qkv layout: [SEQ][3*HID] fp32,
// q at col h*64, k at 1024+h*64, v at 2048+h*64.
__global__ __launch_bounds__(256) void attn_sparse(const float* __restrict__ qkv,
                                                   float* __restrict__ aout) {
    const int i = blockIdx.x;
    const int h = blockIdx.y;
    const int tid = threadIdx.x;

    __shared__ float sc[SEQ];
    __shared__ float qsh[HD];
    __shared__ float red[256];

    const float scale = 0.125f;  // 1/sqrt(64)

    const float* qrow = qkv + (size_t)i * (3 * HID) + h * HD;
    if (tid < HD) qsh[tid] = qrow[tid];
    __syncthreads();

    const bool grow = (i % GSTR) == 0;       // global row attends to everything
    const int lo = max(i - WIN, 0);
    const int hi = min(i + WIN, SEQ - 1);
    const int wlen = hi - lo + 1;
    const int nbefore = (lo + 63) >> 6;      // globals strictly before window
    const int mafter0 = (hi >> 6) + 1;       // first global index after window
    const int nafter = (SEQ / GSTR) - mafter0;
    const int nlist = grow ? SEQ : (wlen + nbefore + nafter);

    // ---- scores ----
    float lmax = -3.0e38f;
    for (int t = tid; t < nlist; t += 256) {
        int j;
        if (grow) j = t;
        else if (t < wlen) j = lo + t;
        else {
            int t2 = t - wlen;
            j = (t2 < nbefore) ? (t2 << 6) : ((mafter0 + (t2 - nbefore)) << 6);
        }
        const float* krow = qkv + (size_t)j * (3 * HID) + HID + h * HD;
        float s = 0.f;
        #pragma unroll
        for (int d = 0; d < HD; ++d) s += qsh[d] * krow[d];
        s *= scale;
        sc[t] = s;
        lmax = fmaxf(lmax, s);
    }

    // ---- max reduce ----
    red[tid] = lmax;
    __syncthreads();
    for (int st = 128; st > 0; st >>= 1) {
        if (tid < st) red[tid] = fmaxf(red[tid], red[tid + st]);
        __syncthreads();
    }
    const float mx = red[0];
    __syncthreads();

    // ---- exp + sum reduce ----
    float lsum = 0.f;
    for (int t = tid; t < nlist; t += 256) {
        float e = __expf(sc[t] - mx);
        sc[t] = e;
        lsum += e;
    }
    red[tid] = lsum;
    __syncthreads();
    for (int st = 128; st > 0; st >>= 1) {
        if (tid < st) red[tid] += red[tid + st];
        __syncthreads();
    }
    const float inv = 1.0f / red[0];
    __syncthreads();

    // ---- PV: 4 groups of 64 lanes; lane d accumulates output dim d ----
    const int d = tid & 63;
    const int grp = tid >> 6;
    float acc = 0.f;
    for (int t = grp; t < nlist; t += 4) {
        int j;
        if (grow) j = t;
        else if (t < wlen) j = lo + t;
        else {
            int t2 = t - wlen;
            j = (t2 < nbefore) ? (t2 << 6) : ((mafter0 + (t2 - nbefore)) << 6);
        }
        acc += sc[t] * qkv[(size_t)j * (3 * HID) + 2 * HID + h * HD + d];
    }
    red[tid] = acc;
    __syncthreads();
    if (grp == 0) {
        float o = (red[tid] + red[tid + 64] + red[tid + 128] + red[tid + 192]) * inv;
        aout[(size_t)i * HID + h * HD + d] = o;
    }
}

extern "C" void kernel_launch(void* const* d_in, const int* in_sizes, int n_in,
                              void* d_out, int out_size, void* d_ws, size_t ws_size,
                              hipStream_t stream) {
    const float* x    = (const float*)d_in[0];   // [2048,1024] fp32
    const float* Wqkv = (const float*)d_in[1];   // [3072,1024] fp32
    const float* Wout = (const float*)d_in[2];   // [1024,1024] fp32
    float* out = (float*)d_out;                  // [2048,1024] fp32

    float* qkv  = (float*)d_ws;                  // 2048*3072 fp32 = 25.2 MB
    float* aout = qkv + (size_t)SEQ * 3 * HID;   // 2048*1024 fp32 =  8.4 MB

    // 1) qkv = x @ Wqkv^T
    gemm_abt<<<dim3(3 * HID / 64, SEQ / 64), 256, 0, stream>>>(x, Wqkv, qkv, SEQ, 3 * HID, HID);

    // 2) sparse attention per (query, head)
    attn_sparse<<<dim3(SEQ, NH), 256, 0, stream>>>(qkv, aout);

    // 3) out = aout @ Wout^T
    gemm_abt<<<dim3(HID / 64, SEQ / 64), 256, 0, stream>>>(aout, Wout, out, SEQ, HID, HID);
}

// Round 3
// 669.563 us; speedup vs baseline: 3.7521x; 3.7521x over previous
//
#include <hip/hip_runtime.h>
#include <hip/hip_bf16.h>
#include <math.h>

// Problem constants (B=1)
#define SEQ   2048
#define HID   1024
#define NH    16
#define HD    64
#define WIN   128
#define GSTR  64

// ---------------------------------------------------------------------------
// GEMM: C[M,N] = A[M,K] @ B[N,K]^T (all fp32), 64x64 tile, BK=16, 256 thr.
// ---------------------------------------------------------------------------
__global__ __launch_bounds__(256) void gemm_abt(const float* __restrict__ A,
                                                const float* __restrict__ B,
                                                float* __restrict__ C,
                                                int M, int N, int K) {
    __shared__ float As[16][64];
    __shared__ float Bs[16][64];
    const int tx = threadIdx.x & 15;
    const int ty = threadIdx.x >> 4;
    const int bm = blockIdx.y * 64;
    const int bn = blockIdx.x * 64;

    float acc[4][4] = {};

    for (int k0 = 0; k0 < K; k0 += 16) {
        for (int t = threadIdx.x; t < 64 * 16; t += 256) {
            int m = t >> 4, kk = t & 15;
            As[kk][m] = A[(size_t)(bm + m) * K + k0 + kk];
        }
        for (int t = threadIdx.x; t < 64 * 16; t += 256) {
            int n = t >> 4, kk = t & 15;
            Bs[kk][n] = B[(size_t)(bn + n) * K + k0 + kk];
        }
        __syncthreads();
        #pragma unroll
        for (int kk = 0; kk < 16; ++kk) {
            float a[4], b[4];
            #pragma unroll
            for (int i = 0; i < 4; ++i) a[i] = As[kk][ty * 4 + i];
            #pragma unroll
            for (int j = 0; j < 4; ++j) b[j] = Bs[kk][tx * 4 + j];
            #pragma unroll
            for (int i = 0; i < 4; ++i)
                #pragma unroll
                for (int j = 0; j < 4; ++j)
                    acc[i][j] += a[i] * b[j];
        }
        __syncthreads();
    }
    #pragma unroll
    for (int i = 0; i < 4; ++i)
        #pragma unroll
        for (int j = 0; j < 4; ++j)
            C[(size_t)(bm + ty * 4 + i) * N + bn + tx * 4 + j] = acc[i][j];
}

// ---------------------------------------------------------------------------
// Banded+global-column attention (flash-style), fp32.
// Block = (query tile of 64, head). 256 threads: q = tid>>2, r = tid&3.
// Thread (q,r) owns keys c = 4*kk + r (kk=0..15) and dims d = r*16..r*16+15.
// Window tiles: mask |i-j|<=WIN only. Gather tile (last): all 32 global cols,
// mask |i-j|>WIN. Exact disjoint cover of the Longformer mask for non-global
// rows; global rows are overwritten by attn_global afterwards.
// ---------------------------------------------------------------------------
__global__ __launch_bounds__(256) void attn_banded(const float* __restrict__ qkv,
                                                   float* __restrict__ aout) {
    const int bq = blockIdx.x;          // query tile index (0..31)
    const int h  = blockIdx.y;          // head
    const int tid = threadIdx.x;
    const int q = tid >> 2;             // 0..63 query within tile
    const int r = tid & 3;              // 0..3
    const int lane = tid & 63;
    const int q0 = bq * 64;
    const int i = q0 + q;               // global query index

    __shared__ float4 Qs[64][17];
    __shared__ float4 Ks[64][17];
    __shared__ float4 Vs[64][17];

    // Load Q tile (64 rows x 16 float4)
    for (int f = tid; f < 1024; f += 256) {
        int row = f >> 4, c4 = f & 15;
        const float4* qp = (const float4*)(qkv + (size_t)(q0 + row) * (3 * HID) + h * HD);
        Qs[row][c4] = qp[c4];
    }

    float m = -1.0e30f;
    float l = 0.0f;
    float4 Oa[4];
    #pragma unroll
    for (int mi = 0; mi < 4; ++mi) { Oa[mi].x = Oa[mi].y = Oa[mi].z = Oa[mi].w = 0.f; }

    const int t0 = max(bq - 2, 0);
    const int t1 = min(bq + 2, SEQ / 64 - 1);

    for (int tt = t0; tt <= t1 + 1; ++tt) {
        const bool gather = (tt == t1 + 1);
        __syncthreads();
        if (!gather) {
            const int jb = tt * 64;
            for (int f = tid; f < 1024; f += 256) {
                int row = f >> 4, c4 = f & 15;
                const float* base = qkv + (size_t)(jb + row) * (3 * HID) + h * HD;
                Ks[row][c4] = ((const float4*)(base + HID))[c4];
                Vs[row][c4] = ((const float4*)(base + 2 * HID))[c4];
            }
        } else {
            for (int f = tid; f < 512; f += 256) {
                int row = f >> 4, c4 = f & 15;            // row 0..31 -> key row*64
                const float* base = qkv + (size_t)(row << 6) * (3 * HID) + h * HD;
                Ks[row][c4] = ((const float4*)(base + HID))[c4];
                Vs[row][c4] = ((const float4*)(base + 2 * HID))[c4];
            }
        }
        __syncthreads();

        // ---- scores for this thread's 16 keys ----
        float s[16];
        #pragma unroll
        for (int kk = 0; kk < 16; ++kk) s[kk] = 0.f;
        for (int d4 = 0; d4 < 16; ++d4) {
            float4 qv = Qs[q][d4];
            #pragma unroll
            for (int kk = 0; kk < 16; ++kk) {
                float4 kv = Ks[(kk << 2) + r][d4];
                s[kk] += qv.x * kv.x + qv.y * kv.y + qv.z * kv.z + qv.w * kv.w;
            }
        }
        // ---- mask + scale ----
        #pragma unroll
        for (int kk = 0; kk < 16; ++kk) {
            int c = (kk << 2) + r;
            int j = gather ? (c << 6) : (tt * 64 + c);
            bool valid = gather ? ((c < 32) && (abs(i - j) > WIN))
                                : (abs(i - j) <= WIN);
            s[kk] = valid ? s[kk] * 0.125f : -1.0e30f;
        }
        // ---- online softmax update ----
        float tm = s[0];
        #pragma unroll
        for (int kk = 1; kk < 16; ++kk) tm = fmaxf(tm, s[kk]);
        tm = fmaxf(tm, __shfl_xor(tm, 1));
        tm = fmaxf(tm, __shfl_xor(tm, 2));
        float mn = fmaxf(m, tm);
        float alpha = __expf(m - mn);
        float p[16];
        float ts = 0.f;
        #pragma unroll
        for (int kk = 0; kk < 16; ++kk) {
            p[kk] = (s[kk] > -1.0e29f) ? __expf(s[kk] - mn) : 0.f;
            ts += p[kk];
        }
        ts += __shfl_xor(ts, 1);
        ts += __shfl_xor(ts, 2);
        l = l * alpha + ts;
        m = mn;
        #pragma unroll
        for (int mi = 0; mi < 4; ++mi) {
            Oa[mi].x *= alpha; Oa[mi].y *= alpha; Oa[mi].z *= alpha; Oa[mi].w *= alpha;
        }
        // ---- PV accumulate: O[d] += sum_c P[c] * V[c][d] ----
        #pragma unroll
        for (int c = 0; c < 64; ++c) {
            float pv = __shfl(p[c >> 2], (lane & ~3) | (c & 3));
            #pragma unroll
            for (int mi = 0; mi < 4; ++mi) {
                float4 vv = Vs[c][(r << 2) + mi];
                Oa[mi].x += pv * vv.x; Oa[mi].y += pv * vv.y;
                Oa[mi].z += pv * vv.z; Oa[mi].w += pv * vv.w;
            }
        }
    }

    const float inv = 1.0f / l;
    float4* outp = (float4*)(aout + (size_t)i * HID + h * HD + (r << 4));
    #pragma unroll
    for (int mi = 0; mi < 4; ++mi) {
        float4 o = Oa[mi];
        o.x *= inv; o.y *= inv; o.z *= inv; o.w *= inv;
        outp[mi] = o;
    }
}

// ---------------------------------------------------------------------------
// Dense attention for global rows (i % GSTR == 0): overwrite their output.
// Block = (g, h), g = 0..31 -> i = g*64. 256 threads, two-pass softmax.
// ---------------------------------------------------------------------------
__global__ __launch_bounds__(256) void attn_global(const float* __restrict__ qkv,
                                                   float* __restrict__ aout) {
    const int g = blockIdx.x;
    const int h = blockIdx.y;
    const int i = g * GSTR;
    const int tid = threadIdx.x;

    __shared__ float4 q4[16];
    __shared__ float sc[SEQ];
    __shared__ float red[256];
    __shared__ float4 ored[16][17];

    if (tid < 16)
        q4[tid] = ((const float4*)(qkv + (size_t)i * (3 * HID) + h * HD))[tid];
    __syncthreads();

    float lmax = -3.0e38f;
    for (int j = tid; j < SEQ; j += 256) {
        const float4* kp = (const float4*)(qkv + (size_t)j * (3 * HID) + HID + h * HD);
        float s = 0.f;
        #pragma unroll
        for (int d4 = 0; d4 < 16; ++d4) {
            float4 kv = kp[d4];
            float4 qv = q4[d4];
            s += qv.x * kv.x + qv.y * kv.y + qv.z * kv.z + qv.w * kv.w;
        }
        s *= 0.125f;
        sc[j] = s;
        lmax = fmaxf(lmax, s);
    }
    red[tid] = lmax;
    __syncthreads();
    for (int st = 128; st > 0; st >>= 1) {
        if (tid < st) red[tid] = fmaxf(red[tid], red[tid + st]);
        __syncthreads();
    }
    const float mx = red[0];
    __syncthreads();

    float lsum = 0.f;
    for (int j = tid; j < SEQ; j += 256) {
        float e = __expf(sc[j] - mx);
        sc[j] = e;
        lsum += e;
    }
    red[tid] = lsum;
    __syncthreads();
    for (int st = 128; st > 0; st >>= 1) {
        if (tid < st) red[tid] += red[tid + st];
        __syncthreads();
    }
    const float inv = 1.0f / red[0];
    __syncthreads();

    // PV: thread -> (jg = tid>>4, d4 = tid&15); coalesced float4 V reads
    const int d4 = tid & 15;
    const int jg = tid >> 4;
    float4 o; o.x = o.y = o.z = o.w = 0.f;
    for (int j = jg; j < SEQ; j += 16) {
        const float4* vp = (const float4*)(qkv + (size_t)j * (3 * HID) + 2 * HID + h * HD);
        float4 vv = vp[d4];
        float pv = sc[j];
        o.x += pv * vv.x; o.y += pv * vv.y; o.z += pv * vv.z; o.w += pv * vv.w;
    }
    ored[jg][d4] = o;
    __syncthreads();
    if (tid < 16) {
        float4 acc = ored[0][tid];
        #pragma unroll
        for (int k = 1; k < 16; ++k) {
            float4 t = ored[k][tid];
            acc.x += t.x; acc.y += t.y; acc.z += t.z; acc.w += t.w;
        }
        acc.x *= inv; acc.y *= inv; acc.z *= inv; acc.w *= inv;
        ((float4*)(aout + (size_t)i * HID + h * HD))[tid] = acc;
    }
}

extern "C" void kernel_launch(void* const* d_in, const int* in_sizes, int n_in,
                              void* d_out, int out_size, void* d_ws, size_t ws_size,
                              hipStream_t stream) {
    const float* x    = (const float*)d_in[0];   // [2048,1024] fp32
    const float* Wqkv = (const float*)d_in[1];   // [3072,1024] fp32
    const float* Wout = (const float*)d_in[2];   // [1024,1024] fp32
    float* out = (float*)d_out;                  // [2048,1024] fp32

    float* qkv  = (float*)d_ws;                  // 2048*3072 fp32 = 25.2 MB
    float* aout = qkv + (size_t)SEQ * 3 * HID;   // 2048*1024 fp32 =  8.4 MB

    // 1) qkv = x @ Wqkv^T
    gemm_abt<<<dim3(3 * HID / 64, SEQ / 64), 256, 0, stream>>>(x, Wqkv, qkv, SEQ, 3 * HID, HID);

    // 2a) banded + global-column attention for all rows
    attn_banded<<<dim3(SEQ / 64, NH), 256, 0, stream>>>(qkv, aout);

    // 2b) dense attention for global rows (overwrites those rows)
    attn_global<<<dim3(SEQ / GSTR, NH), 256, 0, stream>>>(qkv, aout);

    // 3) out = aout @ Wout^T
    gemm_abt<<<dim3(HID / 64, SEQ / 64), 256, 0, stream>>>(aout, Wout, out, SEQ, HID, HID);
}

// Round 4
// 308.700 us; speedup vs baseline: 8.1382x; 2.1690x over previous
//
#include <hip/hip_runtime.h>
#include <hip/hip_bf16.h>
#include <math.h>

// Problem constants (B=1)
#define SEQ   2048
#define HID   1024
#define NH    16
#define HD    64
#define WIN   128
#define GSTR  64

typedef __attribute__((ext_vector_type(8))) short short8;   // 8 bf16 = 4 VGPRs
typedef __attribute__((ext_vector_type(4))) float f32x4;    // MFMA C/D

// RNE fp32 -> bf16 bits (finite inputs)
__device__ inline unsigned short bf16b(float f) {
    union { float f; unsigned int u; } v; v.f = f;
    return (unsigned short)((v.u + 0x7FFFu + ((v.u >> 16) & 1u)) >> 16);
}

// ---------------------------------------------------------------------------
// MFMA GEMM: C[M,N] = A[M,K] @ B[N,K]^T.  A,B fp32 in HBM, converted to bf16
// during LDS staging; fp32 accumulate via v_mfma_f32_16x16x32_bf16.
// 128x128 tile, BK=32, 256 threads (4 waves), wave computes 64x64 via 4x4
// grid of 16x16 accumulators. LDS row stride 40 bf16 (80 B) -> 2-way bank
// aliasing on ds_read_b128 (free per m136). M,N,K must be multiples of 128/32.
// ---------------------------------------------------------------------------
__global__ __launch_bounds__(256) void gemm_abt_mfma(const float* __restrict__ A,
                                                     const float* __restrict__ B,
                                                     float* __restrict__ C,
                                                     int M, int N, int K) {
    __shared__ unsigned short As[128 * 40];
    __shared__ unsigned short Bs[128 * 40];

    const int tid  = threadIdx.x;
    const int wave = tid >> 6;
    const int lane = tid & 63;
    const int quad = lane >> 4;     // 0..3
    const int l15  = lane & 15;     // 0..15
    const int bm = blockIdx.y * 128;
    const int bn = blockIdx.x * 128;
    const int wm = (wave & 1) * 64;
    const int wn = (wave >> 1) * 64;

    f32x4 acc[4][4];
    #pragma unroll
    for (int i = 0; i < 4; ++i)
        #pragma unroll
        for (int j = 0; j < 4; ++j)
            acc[i][j] = (f32x4){0.f, 0.f, 0.f, 0.f};

    for (int k0 = 0; k0 < K; k0 += 32) {
        // ---- stage: 128 rows x 32 cols fp32 -> bf16 LDS, A and B ----
        #pragma unroll
        for (int it = 0; it < 4; ++it) {
            const int c    = tid + it * 256;   // float4-chunk id 0..1023
            const int row  = c >> 3;           // 0..127
            const int col4 = c & 7;            // 0..7 (float4 within BK=32)
            float4 af = *(const float4*)(A + (size_t)(bm + row) * K + k0 + col4 * 4);
            float4 bf = *(const float4*)(B + (size_t)(bn + row) * K + k0 + col4 * 4);
            ushort4 ap, bp;
            ap.x = bf16b(af.x); ap.y = bf16b(af.y); ap.z = bf16b(af.z); ap.w = bf16b(af.w);
            bp.x = bf16b(bf.x); bp.y = bf16b(bf.y); bp.z = bf16b(bf.z); bp.w = bf16b(bf.w);
            *(ushort4*)&As[row * 40 + col4 * 4] = ap;
            *(ushort4*)&Bs[row * 40 + col4 * 4] = bp;
        }
        __syncthreads();

        // ---- fragments: A[m=l15][k=quad*8+j], B[n=l15][k=quad*8+j] ----
        short8 a[4], b[4];
        #pragma unroll
        for (int im = 0; im < 4; ++im)
            a[im] = *(const short8*)&As[(wm + im * 16 + l15) * 40 + quad * 8];
        #pragma unroll
        for (int jn = 0; jn < 4; ++jn)
            b[jn] = *(const short8*)&Bs[(wn + jn * 16 + l15) * 40 + quad * 8];

        #pragma unroll
        for (int im = 0; im < 4; ++im)
            #pragma unroll
            for (int jn = 0; jn < 4; ++jn)
                acc[im][jn] = __builtin_amdgcn_mfma_f32_16x16x32_bf16(
                    a[im], b[jn], acc[im][jn], 0, 0, 0);
        __syncthreads();
    }

    // ---- epilogue: C/D layout col=lane&15, row=quad*4+reg ----
    #pragma unroll
    for (int im = 0; im < 4; ++im)
        #pragma unroll
        for (int jn = 0; jn < 4; ++jn)
            #pragma unroll
            for (int reg = 0; reg < 4; ++reg)
                C[(size_t)(bm + wm + im * 16 + quad * 4 + reg) * N
                  + bn + wn + jn * 16 + l15] = acc[im][jn][reg];
}

// ---------------------------------------------------------------------------
// Banded+global-column attention (flash-style), fp32. (unchanged from R3)
// ---------------------------------------------------------------------------
__global__ __launch_bounds__(256) void attn_banded(const float* __restrict__ qkv,
                                                   float* __restrict__ aout) {
    const int bq = blockIdx.x;
    const int h  = blockIdx.y;
    const int tid = threadIdx.x;
    const int q = tid >> 2;
    const int r = tid & 3;
    const int lane = tid & 63;
    const int q0 = bq * 64;
    const int i = q0 + q;

    __shared__ float4 Qs[64][17];
    __shared__ float4 Ks[64][17];
    __shared__ float4 Vs[64][17];

    for (int f = tid; f < 1024; f += 256) {
        int row = f >> 4, c4 = f & 15;
        const float4* qp = (const float4*)(qkv + (size_t)(q0 + row) * (3 * HID) + h * HD);
        Qs[row][c4] = qp[c4];
    }

    float m = -1.0e30f;
    float l = 0.0f;
    float4 Oa[4];
    #pragma unroll
    for (int mi = 0; mi < 4; ++mi) { Oa[mi].x = Oa[mi].y = Oa[mi].z = Oa[mi].w = 0.f; }

    const int t0 = max(bq - 2, 0);
    const int t1 = min(bq + 2, SEQ / 64 - 1);

    for (int tt = t0; tt <= t1 + 1; ++tt) {
        const bool gather = (tt == t1 + 1);
        __syncthreads();
        if (!gather) {
            const int jb = tt * 64;
            for (int f = tid; f < 1024; f += 256) {
                int row = f >> 4, c4 = f & 15;
                const float* base = qkv + (size_t)(jb + row) * (3 * HID) + h * HD;
                Ks[row][c4] = ((const float4*)(base + HID))[c4];
                Vs[row][c4] = ((const float4*)(base + 2 * HID))[c4];
            }
        } else {
            for (int f = tid; f < 512; f += 256) {
                int row = f >> 4, c4 = f & 15;
                const float* base = qkv + (size_t)(row << 6) * (3 * HID) + h * HD;
                Ks[row][c4] = ((const float4*)(base + HID))[c4];
                Vs[row][c4] = ((const float4*)(base + 2 * HID))[c4];
            }
        }
        __syncthreads();

        float s[16];
        #pragma unroll
        for (int kk = 0; kk < 16; ++kk) s[kk] = 0.f;
        for (int d4 = 0; d4 < 16; ++d4) {
            float4 qv = Qs[q][d4];
            #pragma unroll
            for (int kk = 0; kk < 16; ++kk) {
                float4 kv = Ks[(kk << 2) + r][d4];
                s[kk] += qv.x * kv.x + qv.y * kv.y + qv.z * kv.z + qv.w * kv.w;
            }
        }
        #pragma unroll
        for (int kk = 0; kk < 16; ++kk) {
            int c = (kk << 2) + r;
            int j = gather ? (c << 6) : (tt * 64 + c);
            bool valid = gather ? ((c < 32) && (abs(i - j) > WIN))
                                : (abs(i - j) <= WIN);
            s[kk] = valid ? s[kk] * 0.125f : -1.0e30f;
        }
        float tm = s[0];
        #pragma unroll
        for (int kk = 1; kk < 16; ++kk) tm = fmaxf(tm, s[kk]);
        tm = fmaxf(tm, __shfl_xor(tm, 1));
        tm = fmaxf(tm, __shfl_xor(tm, 2));
        float mn = fmaxf(m, tm);
        float alpha = __expf(m - mn);
        float p[16];
        float ts = 0.f;
        #pragma unroll
        for (int kk = 0; kk < 16; ++kk) {
            p[kk] = (s[kk] > -1.0e29f) ? __expf(s[kk] - mn) : 0.f;
            ts += p[kk];
        }
        ts += __shfl_xor(ts, 1);
        ts += __shfl_xor(ts, 2);
        l = l * alpha + ts;
        m = mn;
        #pragma unroll
        for (int mi = 0; mi < 4; ++mi) {
            Oa[mi].x *= alpha; Oa[mi].y *= alpha; Oa[mi].z *= alpha; Oa[mi].w *= alpha;
        }
        #pragma unroll
        for (int c = 0; c < 64; ++c) {
            float pv = __shfl(p[c >> 2], (lane & ~3) | (c & 3));
            #pragma unroll
            for (int mi = 0; mi < 4; ++mi) {
                float4 vv = Vs[c][(r << 2) + mi];
                Oa[mi].x += pv * vv.x; Oa[mi].y += pv * vv.y;
                Oa[mi].z += pv * vv.z; Oa[mi].w += pv * vv.w;
            }
        }
    }

    const float inv = 1.0f / l;
    float4* outp = (float4*)(aout + (size_t)i * HID + h * HD + (r << 4));
    #pragma unroll
    for (int mi = 0; mi < 4; ++mi) {
        float4 o = Oa[mi];
        o.x *= inv; o.y *= inv; o.z *= inv; o.w *= inv;
        outp[mi] = o;
    }
}

// ---------------------------------------------------------------------------
// Dense attention for global rows (unchanged from R3)
// ---------------------------------------------------------------------------
__global__ __launch_bounds__(256) void attn_global(const float* __restrict__ qkv,
                                                   float* __restrict__ aout) {
    const int g = blockIdx.x;
    const int h = blockIdx.y;
    const int i = g * GSTR;
    const int tid = threadIdx.x;

    __shared__ float4 q4[16];
    __shared__ float sc[SEQ];
    __shared__ float red[256];
    __shared__ float4 ored[16][17];

    if (tid < 16)
        q4[tid] = ((const float4*)(qkv + (size_t)i * (3 * HID) + h * HD))[tid];
    __syncthreads();

    float lmax = -3.0e38f;
    for (int j = tid; j < SEQ; j += 256) {
        const float4* kp = (const float4*)(qkv + (size_t)j * (3 * HID) + HID + h * HD);
        float s = 0.f;
        #pragma unroll
        for (int d4 = 0; d4 < 16; ++d4) {
            float4 kv = kp[d4];
            float4 qv = q4[d4];
            s += qv.x * kv.x + qv.y * kv.y + qv.z * kv.z + qv.w * kv.w;
        }
        s *= 0.125f;
        sc[j] = s;
        lmax = fmaxf(lmax, s);
    }
    red[tid] = lmax;
    __syncthreads();
    for (int st = 128; st > 0; st >>= 1) {
        if (tid < st) red[tid] = fmaxf(red[tid], red[tid + st]);
        __syncthreads();
    }
    const float mx = red[0];
    __syncthreads();

    float lsum = 0.f;
    for (int j = tid; j < SEQ; j += 256) {
        float e = __expf(sc[j] - mx);
        sc[j] = e;
        lsum += e;
    }
    red[tid] = lsum;
    __syncthreads();
    for (int st = 128; st > 0; st >>= 1) {
        if (tid < st) red[tid] += red[tid + st];
        __syncthreads();
    }
    const float inv = 1.0f / red[0];
    __syncthreads();

    const int d4 = tid & 15;
    const int jg = tid >> 4;
    float4 o; o.x = o.y = o.z = o.w = 0.f;
    for (int j = jg; j < SEQ; j += 16) {
        const float4* vp = (const float4*)(qkv + (size_t)j * (3 * HID) + 2 * HID + h * HD);
        float4 vv = vp[d4];
        float pv = sc[j];
        o.x += pv * vv.x; o.y += pv * vv.y; o.z += pv * vv.z; o.w += pv * vv.w;
    }
    ored[jg][d4] = o;
    __syncthreads();
    if (tid < 16) {
        float4 acc = ored[0][tid];
        #pragma unroll
        for (int k = 1; k < 16; ++k) {
            float4 t = ored[k][tid];
            acc.x += t.x; acc.y += t.y; acc.z += t.z; acc.w += t.w;
        }
        acc.x *= inv; acc.y *= inv; acc.z *= inv; acc.w *= inv;
        ((float4*)(aout + (size_t)i * HID + h * HD))[tid] = acc;
    }
}

extern "C" void kernel_launch(void* const* d_in, const int* in_sizes, int n_in,
                              void* d_out, int out_size, void* d_ws, size_t ws_size,
                              hipStream_t stream) {
    const float* x    = (const float*)d_in[0];   // [2048,1024] fp32
    const float* Wqkv = (const float*)d_in[1];   // [3072,1024] fp32
    const float* Wout = (const float*)d_in[2];   // [1024,1024] fp32
    float* out = (float*)d_out;                  // [2048,1024] fp32

    float* qkv  = (float*)d_ws;                  // 2048*3072 fp32 = 25.2 MB
    float* aout = qkv + (size_t)SEQ * 3 * HID;   // 2048*1024 fp32 =  8.4 MB

    // 1) qkv = x @ Wqkv^T  (bf16 MFMA, fp32 accumulate)
    gemm_abt_mfma<<<dim3(3 * HID / 128, SEQ / 128), 256, 0, stream>>>(
        x, Wqkv, qkv, SEQ, 3 * HID, HID);

    // 2a) banded + global-column attention for all rows
    attn_banded<<<dim3(SEQ / 64, NH), 256, 0, stream>>>(qkv, aout);

    // 2b) dense attention for global rows (overwrites those rows)
    attn_global<<<dim3(SEQ / GSTR, NH), 256, 0, stream>>>(qkv, aout);

    // 3) out = aout @ Wout^T  (bf16 MFMA, fp32 accumulate)
    gemm_abt_mfma<<<dim3(HID / 128, SEQ / 128), 256, 0, stream>>>(
        aout, Wout, out, SEQ, HID, HID);
}

// Round 5
// 281.749 us; speedup vs baseline: 8.9166x; 1.0957x over previous
//
#include <hip/hip_runtime.h>
#include <hip/hip_bf16.h>
#include <math.h>

// Problem constants (B=1)
#define SEQ   2048
#define HID   1024
#define NH    16
#define HD    64
#define WIN   128
#define GSTR  64

typedef __attribute__((ext_vector_type(8))) short short8;   // 8 bf16 = 4 VGPRs
typedef __attribute__((ext_vector_type(4))) float f32x4;    // MFMA C/D

// RNE fp32 -> bf16 bits (finite inputs)
__device__ inline unsigned short bf16b(float f) {
    union { float f; unsigned int u; } v; v.f = f;
    return (unsigned short)((v.u + 0x7FFFu + ((v.u >> 16) & 1u)) >> 16);
}

// ---------------------------------------------------------------------------
// MFMA GEMM: C[M,N] = A[M,K] @ B[N,K]^T.  A,B fp32 in HBM, converted to bf16
// during LDS staging; fp32 accumulate via v_mfma_f32_16x16x32_bf16.
// 128x128 tile, BK=32, 256 threads (4 waves). (unchanged from R4)
// ---------------------------------------------------------------------------
__global__ __launch_bounds__(256) void gemm_abt_mfma(const float* __restrict__ A,
                                                     const float* __restrict__ B,
                                                     float* __restrict__ C,
                                                     int M, int N, int K) {
    __shared__ unsigned short As[128 * 40];
    __shared__ unsigned short Bs[128 * 40];

    const int tid  = threadIdx.x;
    const int wave = tid >> 6;
    const int lane = tid & 63;
    const int quad = lane >> 4;
    const int l15  = lane & 15;
    const int bm = blockIdx.y * 128;
    const int bn = blockIdx.x * 128;
    const int wm = (wave & 1) * 64;
    const int wn = (wave >> 1) * 64;

    f32x4 acc[4][4];
    #pragma unroll
    for (int i = 0; i < 4; ++i)
        #pragma unroll
        for (int j = 0; j < 4; ++j)
            acc[i][j] = (f32x4){0.f, 0.f, 0.f, 0.f};

    for (int k0 = 0; k0 < K; k0 += 32) {
        #pragma unroll
        for (int it = 0; it < 4; ++it) {
            const int c    = tid + it * 256;
            const int row  = c >> 3;
            const int col4 = c & 7;
            float4 af = *(const float4*)(A + (size_t)(bm + row) * K + k0 + col4 * 4);
            float4 bf = *(const float4*)(B + (size_t)(bn + row) * K + k0 + col4 * 4);
            ushort4 ap, bp;
            ap.x = bf16b(af.x); ap.y = bf16b(af.y); ap.z = bf16b(af.z); ap.w = bf16b(af.w);
            bp.x = bf16b(bf.x); bp.y = bf16b(bf.y); bp.z = bf16b(bf.z); bp.w = bf16b(bf.w);
            *(ushort4*)&As[row * 40 + col4 * 4] = ap;
            *(ushort4*)&Bs[row * 40 + col4 * 4] = bp;
        }
        __syncthreads();

        short8 a[4], b[4];
        #pragma unroll
        for (int im = 0; im < 4; ++im)
            a[im] = *(const short8*)&As[(wm + im * 16 + l15) * 40 + quad * 8];
        #pragma unroll
        for (int jn = 0; jn < 4; ++jn)
            b[jn] = *(const short8*)&Bs[(wn + jn * 16 + l15) * 40 + quad * 8];

        #pragma unroll
        for (int im = 0; im < 4; ++im)
            #pragma unroll
            for (int jn = 0; jn < 4; ++jn)
                acc[im][jn] = __builtin_amdgcn_mfma_f32_16x16x32_bf16(
                    a[im], b[jn], acc[im][jn], 0, 0, 0);
        __syncthreads();
    }

    #pragma unroll
    for (int im = 0; im < 4; ++im)
        #pragma unroll
        for (int jn = 0; jn < 4; ++jn)
            #pragma unroll
            for (int reg = 0; reg < 4; ++reg)
                C[(size_t)(bm + wm + im * 16 + quad * 4 + reg) * N
                  + bn + wn + jn * 16 + l15] = acc[im][jn][reg];
}

// ---------------------------------------------------------------------------
// Fused attention, fp32.
// blockIdx.x < 32:  banded+gather flash tile (64 queries x head), 4x4 register
//                   tiling: thread (ty,tx) owns queries ty*4+i, keys j*16+tx,
//                   O dims tx*4..tx*4+3. P routed through LDS for PV.
//                   Skips storing global rows (q==0) — those are written by
//                   the global blocks below (race-free).
// blockIdx.x >= 32: dense attention for global row i=(bx-32)*64.
// Shared memory overlaid via one 69632-byte buffer.
// ---------------------------------------------------------------------------
__global__ __launch_bounds__(256) void attn_fused(const float* __restrict__ qkv,
                                                  float* __restrict__ aout) {
    __shared__ __align__(16) unsigned char smem[69632];
    const int tid = threadIdx.x;
    const int h = blockIdx.y;

    if (blockIdx.x < 32) {
        // ----------------- banded path -----------------
        float4 (*Qs)[17] = (float4(*)[17])(smem);            // 17408 B
        float4 (*Ks)[17] = (float4(*)[17])(smem + 17408);    // 17408 B
        float4 (*Vs)[17] = (float4(*)[17])(smem + 34816);    // 17408 B
        float*  Ps       = (float*)(smem + 52224);           // 64x68 fp32

        const int bq = blockIdx.x;
        const int tx = tid & 15;
        const int ty = tid >> 4;
        const int q0 = bq * 64;

        for (int f = tid; f < 1024; f += 256) {
            int row = f >> 4, c4 = f & 15;
            Qs[row][c4] = ((const float4*)(qkv + (size_t)(q0 + row) * (3 * HID) + h * HD))[c4];
        }

        float mrow[4], lrow[4];
        float4 Oa[4];
        #pragma unroll
        for (int i = 0; i < 4; ++i) {
            mrow[i] = -1.0e30f; lrow[i] = 0.f;
            Oa[i].x = Oa[i].y = Oa[i].z = Oa[i].w = 0.f;
        }

        const int t0 = max(bq - 2, 0);
        const int t1 = min(bq + 2, SEQ / 64 - 1);

        for (int tt = t0; tt <= t1 + 1; ++tt) {
            const bool gather = (tt == t1 + 1);
            __syncthreads();
            if (!gather) {
                const int jb = tt * 64;
                for (int f = tid; f < 1024; f += 256) {
                    int row = f >> 4, c4 = f & 15;
                    const float* base = qkv + (size_t)(jb + row) * (3 * HID) + h * HD;
                    Ks[row][c4] = ((const float4*)(base + HID))[c4];
                    Vs[row][c4] = ((const float4*)(base + 2 * HID))[c4];
                }
            } else {
                for (int f = tid; f < 512; f += 256) {
                    int row = f >> 4, c4 = f & 15;
                    const float* base = qkv + (size_t)(row << 6) * (3 * HID) + h * HD;
                    Ks[row][c4] = ((const float4*)(base + HID))[c4];
                    Vs[row][c4] = ((const float4*)(base + 2 * HID))[c4];
                }
            }
            __syncthreads();

            // ---- QK^T 4x4 register tile ----
            float s[4][4];
            #pragma unroll
            for (int i = 0; i < 4; ++i)
                #pragma unroll
                for (int j = 0; j < 4; ++j) s[i][j] = 0.f;

            for (int d4 = 0; d4 < 16; ++d4) {
                float4 qv[4], kv[4];
                #pragma unroll
                for (int i = 0; i < 4; ++i) qv[i] = Qs[ty * 4 + i][d4];
                #pragma unroll
                for (int j = 0; j < 4; ++j) kv[j] = Ks[j * 16 + tx][d4];
                #pragma unroll
                for (int i = 0; i < 4; ++i)
                    #pragma unroll
                    for (int j = 0; j < 4; ++j)
                        s[i][j] += qv[i].x * kv[j].x + qv[i].y * kv[j].y
                                 + qv[i].z * kv[j].z + qv[i].w * kv[j].w;
            }

            // ---- mask + scale ----
            #pragma unroll
            for (int i = 0; i < 4; ++i) {
                const int iq = q0 + ty * 4 + i;
                #pragma unroll
                for (int j = 0; j < 4; ++j) {
                    const int c = j * 16 + tx;
                    const int jj = gather ? (c << 6) : (tt * 64 + c);
                    const bool valid = gather ? ((c < 32) && (abs(iq - jj) > WIN))
                                              : (abs(iq - jj) <= WIN);
                    s[i][j] = valid ? s[i][j] * 0.125f : -1.0e30f;
                }
            }

            // ---- online softmax (reduce across tx = low 4 lane bits) ----
            float p[4][4];
            #pragma unroll
            for (int i = 0; i < 4; ++i) {
                float tm = fmaxf(fmaxf(s[i][0], s[i][1]), fmaxf(s[i][2], s[i][3]));
                tm = fmaxf(tm, __shfl_xor(tm, 1));
                tm = fmaxf(tm, __shfl_xor(tm, 2));
                tm = fmaxf(tm, __shfl_xor(tm, 4));
                tm = fmaxf(tm, __shfl_xor(tm, 8));
                const float mn = fmaxf(mrow[i], tm);
                const float alpha = __expf(mrow[i] - mn);
                float ts = 0.f;
                #pragma unroll
                for (int j = 0; j < 4; ++j) {
                    p[i][j] = (s[i][j] > -1.0e29f) ? __expf(s[i][j] - mn) : 0.f;
                    ts += p[i][j];
                }
                ts += __shfl_xor(ts, 1);
                ts += __shfl_xor(ts, 2);
                ts += __shfl_xor(ts, 4);
                ts += __shfl_xor(ts, 8);
                lrow[i] = lrow[i] * alpha + ts;
                mrow[i] = mn;
                Oa[i].x *= alpha; Oa[i].y *= alpha; Oa[i].z *= alpha; Oa[i].w *= alpha;
            }

            // ---- P -> LDS ----
            #pragma unroll
            for (int i = 0; i < 4; ++i)
                #pragma unroll
                for (int j = 0; j < 4; ++j)
                    Ps[(ty * 4 + i) * 68 + j * 16 + tx] = p[i][j];
            __syncthreads();

            // ---- PV: O[q][d] += sum_k P[q][k] V[k][d] ----
            const int nk4 = gather ? 8 : 16;
            for (int k4 = 0; k4 < nk4; ++k4) {
                float4 pr[4];
                #pragma unroll
                for (int i = 0; i < 4; ++i)
                    pr[i] = *(const float4*)&Ps[(ty * 4 + i) * 68 + k4 * 4];
                float4 v0 = Vs[k4 * 4 + 0][tx];
                float4 v1 = Vs[k4 * 4 + 1][tx];
                float4 v2 = Vs[k4 * 4 + 2][tx];
                float4 v3 = Vs[k4 * 4 + 3][tx];
                #pragma unroll
                for (int i = 0; i < 4; ++i) {
                    Oa[i].x += pr[i].x * v0.x + pr[i].y * v1.x + pr[i].z * v2.x + pr[i].w * v3.x;
                    Oa[i].y += pr[i].x * v0.y + pr[i].y * v1.y + pr[i].z * v2.y + pr[i].w * v3.y;
                    Oa[i].z += pr[i].x * v0.z + pr[i].y * v1.z + pr[i].z * v2.z + pr[i].w * v3.z;
                    Oa[i].w += pr[i].x * v0.w + pr[i].y * v1.w + pr[i].z * v2.w + pr[i].w * v3.w;
                }
            }
        }

        // ---- epilogue (skip global rows: q==0 <=> ty==0 && i==0) ----
        #pragma unroll
        for (int i = 0; i < 4; ++i) {
            if (ty == 0 && i == 0) continue;
            const int iq = q0 + ty * 4 + i;
            const float inv = 1.0f / lrow[i];
            float4 o = Oa[i];
            o.x *= inv; o.y *= inv; o.z *= inv; o.w *= inv;
            ((float4*)(aout + (size_t)iq * HID + h * HD))[tx] = o;
        }
    } else {
        // ----------------- global-row path -----------------
        float*  sc  = (float*)(smem);                 // 8192 B
        float*  red = (float*)(smem + 8192);          // 1024 B
        float4* q4  = (float4*)(smem + 9216);         // 256 B
        float4 (*ored)[17] = (float4(*)[17])(smem + 9472);  // 4352 B

        const int g = blockIdx.x - 32;
        const int i = g * GSTR;

        if (tid < 16)
            q4[tid] = ((const float4*)(qkv + (size_t)i * (3 * HID) + h * HD))[tid];
        __syncthreads();

        float lmax = -3.0e38f;
        for (int j = tid; j < SEQ; j += 256) {
            const float4* kp = (const float4*)(qkv + (size_t)j * (3 * HID) + HID + h * HD);
            float s = 0.f;
            #pragma unroll
            for (int d4 = 0; d4 < 16; ++d4) {
                float4 kv = kp[d4];
                float4 qv = q4[d4];
                s += qv.x * kv.x + qv.y * kv.y + qv.z * kv.z + qv.w * kv.w;
            }
            s *= 0.125f;
            sc[j] = s;
            lmax = fmaxf(lmax, s);
        }
        red[tid] = lmax;
        __syncthreads();
        for (int st = 128; st > 0; st >>= 1) {
            if (tid < st) red[tid] = fmaxf(red[tid], red[tid + st]);
            __syncthreads();
        }
        const float mx = red[0];
        __syncthreads();

        float lsum = 0.f;
        for (int j = tid; j < SEQ; j += 256) {
            float e = __expf(sc[j] - mx);
            sc[j] = e;
            lsum += e;
        }
        red[tid] = lsum;
        __syncthreads();
        for (int st = 128; st > 0; st >>= 1) {
            if (tid < st) red[tid] += red[tid + st];
            __syncthreads();
        }
        const float inv = 1.0f / red[0];
        __syncthreads();

        const int d4 = tid & 15;
        const int jg = tid >> 4;
        float4 o; o.x = o.y = o.z = o.w = 0.f;
        for (int j = jg; j < SEQ; j += 16) {
            const float4* vp = (const float4*)(qkv + (size_t)j * (3 * HID) + 2 * HID + h * HD);
            float4 vv = vp[d4];
            float pv = sc[j];
            o.x += pv * vv.x; o.y += pv * vv.y; o.z += pv * vv.z; o.w += pv * vv.w;
        }
        ored[jg][d4] = o;
        __syncthreads();
        if (tid < 16) {
            float4 acc = ored[0][tid];
            #pragma unroll
            for (int k = 1; k < 16; ++k) {
                float4 t = ored[k][tid];
                acc.x += t.x; acc.y += t.y; acc.z += t.z; acc.w += t.w;
            }
            acc.x *= inv; acc.y *= inv; acc.z *= inv; acc.w *= inv;
            ((float4*)(aout + (size_t)i * HID + h * HD))[tid] = acc;
        }
    }
}

extern "C" void kernel_launch(void* const* d_in, const int* in_sizes, int n_in,
                              void* d_out, int out_size, void* d_ws, size_t ws_size,
                              hipStream_t stream) {
    const float* x    = (const float*)d_in[0];   // [2048,1024] fp32
    const float* Wqkv = (const float*)d_in[1];   // [3072,1024] fp32
    const float* Wout = (const float*)d_in[2];   // [1024,1024] fp32
    float* out = (float*)d_out;                  // [2048,1024] fp32

    float* qkv  = (float*)d_ws;                  // 2048*3072 fp32 = 25.2 MB
    float* aout = qkv + (size_t)SEQ * 3 * HID;   // 2048*1024 fp32 =  8.4 MB

    // 1) qkv = x @ Wqkv^T  (bf16 MFMA, fp32 accumulate)
    gemm_abt_mfma<<<dim3(3 * HID / 128, SEQ / 128), 256, 0, stream>>>(
        x, Wqkv, qkv, SEQ, 3 * HID, HID);

    // 2) fused banded + global attention
    attn_fused<<<dim3(SEQ / 64 + SEQ / GSTR, NH), 256, 0, stream>>>(qkv, aout);

    // 3) out = aout @ Wout^T  (bf16 MFMA, fp32 accumulate)
    gemm_abt_mfma<<<dim3(HID / 128, SEQ / 128), 256, 0, stream>>>(
        aout, Wout, out, SEQ, HID, HID);
}

// Round 6
// 244.053 us; speedup vs baseline: 10.2939x; 1.1545x over previous
//
#include <hip/hip_runtime.h>
#include <hip/hip_bf16.h>
#include <math.h>

// Problem constants (B=1)
#define SEQ   2048
#define HID   1024
#define NH    16
#define HD    64
#define WIN   128
#define GSTR  64

typedef __attribute__((ext_vector_type(8))) short short8;   // 8 bf16 = 4 VGPRs
typedef __attribute__((ext_vector_type(4))) float f32x4;    // MFMA C/D

// RNE fp32 -> bf16 bits (finite inputs)
__device__ inline unsigned short bf16b(float f) {
    union { float f; unsigned int u; } v; v.f = f;
    return (unsigned short)((v.u + 0x7FFFu + ((v.u >> 16) & 1u)) >> 16);
}
// bf16 (low/high ushort of a uint) -> fp32: one VALU op each
__device__ inline float blo(unsigned int u) {
    union { unsigned int i; float f; } v; v.i = u << 16; return v.f;
}
__device__ inline float bhi(unsigned int u) {
    union { unsigned int i; float f; } v; v.i = u & 0xFFFF0000u; return v.f;
}

#define GLOAD_LDS16(gp, lp)                                                    \
    __builtin_amdgcn_global_load_lds(                                          \
        (const __attribute__((address_space(1))) unsigned int*)(gp),           \
        (__attribute__((address_space(3))) unsigned int*)(lp), 16, 0, 0)

// ---------------------------------------------------------------------------
// fp32 -> bf16 pre-convert of x, Wqkv, Wout (one grid-stride kernel)
// chunk counts (float4): x 524288, Wqkv 786432, Wout 262144
// ---------------------------------------------------------------------------
__global__ __launch_bounds__(256) void cvt_bf16(const float4* __restrict__ x,
                                                const float4* __restrict__ wq,
                                                const float4* __restrict__ wo,
                                                ushort4* __restrict__ x16,
                                                ushort4* __restrict__ wq16,
                                                ushort4* __restrict__ wo16) {
    for (int idx = blockIdx.x * 256 + threadIdx.x; idx < 1572864;
         idx += gridDim.x * 256) {
        const float4* src; ushort4* dst; int off;
        if (idx < 524288)       { src = x;  dst = x16;  off = idx; }
        else if (idx < 1310720) { src = wq; dst = wq16; off = idx - 524288; }
        else                    { src = wo; dst = wo16; off = idx - 1310720; }
        float4 v = src[off];
        ushort4 o;
        o.x = bf16b(v.x); o.y = bf16b(v.y); o.z = bf16b(v.z); o.w = bf16b(v.w);
        dst[off] = o;
    }
}

// ---------------------------------------------------------------------------
// m97-style MFMA GEMM: C[M,N] = A[M,K] @ B[N,K]^T, A/B bf16 (ushort),
// staged via global_load_lds width=16, unpadded [128][32] LDS layout
// (lane-contiguous; fragment ds_read_b128 spreads 8 accesses/bank = minimum).
// 128x128 tile, BK=32, 256 threads (4 waves), fp32 accumulate.
// OT = unsigned short (bf16 out) or float.
// ---------------------------------------------------------------------------
template <typename OT>
__global__ __launch_bounds__(256) void gemm_bt16(const unsigned short* __restrict__ A,
                                                 const unsigned short* __restrict__ B,
                                                 OT* __restrict__ C,
                                                 int M, int N, int K) {
    __shared__ unsigned short As[128 * 32];
    __shared__ unsigned short Bs[128 * 32];

    const int tid  = threadIdx.x;
    const int wave = tid >> 6;
    const int lane = tid & 63;
    const int quad = lane >> 4;
    const int l15  = lane & 15;
    const int bm = blockIdx.y * 128;
    const int bn = blockIdx.x * 128;
    const int wm = (wave & 1) * 64;
    const int wn = (wave >> 1) * 64;
    const int r0 = wave * 32;          // staging row block for this wave
    const int srow = lane >> 2;        // 0..15
    const int scol = (lane & 3) * 8;   // bf16 col chunk (16 B)

    f32x4 acc[4][4];
    #pragma unroll
    for (int i = 0; i < 4; ++i)
        #pragma unroll
        for (int j = 0; j < 4; ++j)
            acc[i][j] = (f32x4){0.f, 0.f, 0.f, 0.f};

    for (int k0 = 0; k0 < K; k0 += 32) {
        // ---- async stage: each wave fills rows r0..r0+31 of As and Bs ----
        #pragma unroll
        for (int t = 0; t < 2; ++t) {
            const int row = r0 + t * 16 + srow;
            GLOAD_LDS16(A + (size_t)(bm + row) * K + k0 + scol,
                        &As[(size_t)row * 32 + scol]);
            GLOAD_LDS16(B + (size_t)(bn + row) * K + k0 + scol,
                        &Bs[(size_t)row * 32 + scol]);
        }
        __syncthreads();   // compiler drains vmcnt before barrier

        short8 a[4], b[4];
        #pragma unroll
        for (int im = 0; im < 4; ++im)
            a[im] = *(const short8*)&As[(wm + im * 16 + l15) * 32 + quad * 8];
        #pragma unroll
        for (int jn = 0; jn < 4; ++jn)
            b[jn] = *(const short8*)&Bs[(wn + jn * 16 + l15) * 32 + quad * 8];

        #pragma unroll
        for (int im = 0; im < 4; ++im)
            #pragma unroll
            for (int jn = 0; jn < 4; ++jn)
                acc[im][jn] = __builtin_amdgcn_mfma_f32_16x16x32_bf16(
                    a[im], b[jn], acc[im][jn], 0, 0, 0);
        __syncthreads();
    }

    // ---- epilogue: C/D layout col=l15, row=quad*4+reg ----
    #pragma unroll
    for (int im = 0; im < 4; ++im)
        #pragma unroll
        for (int jn = 0; jn < 4; ++jn)
            #pragma unroll
            for (int reg = 0; reg < 4; ++reg) {
                const int r = bm + wm + im * 16 + quad * 4 + reg;
                const int c = bn + wn + jn * 16 + l15;
                float v = acc[im][jn][reg];
                if constexpr (sizeof(OT) == 2)
                    C[(size_t)r * N + c] = (OT)bf16b(v);
                else
                    C[(size_t)r * N + c] = (OT)v;
            }
}

// ---------------------------------------------------------------------------
// Fused attention. qkv16: [SEQ][3*HID] bf16; aout16: [SEQ][HID] bf16.
// blockIdx.x < 32: banded+gather flash tile (fp32 math, bf16 loads).
// blockIdx.x >= 32: dense attention for global row i=(bx-32)*64.
// ---------------------------------------------------------------------------
__global__ __launch_bounds__(256) void attn_fused(const unsigned short* __restrict__ qkv16,
                                                  unsigned short* __restrict__ aout16) {
    __shared__ __align__(16) unsigned char smem[69632];
    const int tid = threadIdx.x;
    const int h = blockIdx.y;

    if (blockIdx.x < 32) {
        // ----------------- banded path -----------------
        float4 (*Qs)[17] = (float4(*)[17])(smem);            // 17408 B
        float4 (*Ks)[17] = (float4(*)[17])(smem + 17408);    // 17408 B
        float4 (*Vs)[17] = (float4(*)[17])(smem + 34816);    // 17408 B
        float*  Ps       = (float*)(smem + 52224);           // 64x68 fp32

        const int bq = blockIdx.x;
        const int tx = tid & 15;
        const int ty = tid >> 4;
        const int q0 = bq * 64;

        // Q tile: 64 rows x 8 uint4 chunks (8 bf16 each)
        for (int f = tid; f < 512; f += 256) {
            int row = f >> 3, c8 = f & 7;
            uint4 u = *(const uint4*)(qkv16 + (size_t)(q0 + row) * (3 * HID) + h * HD + c8 * 8);
            Qs[row][c8 * 2]     = make_float4(blo(u.x), bhi(u.x), blo(u.y), bhi(u.y));
            Qs[row][c8 * 2 + 1] = make_float4(blo(u.z), bhi(u.z), blo(u.w), bhi(u.w));
        }

        float mrow[4], lrow[4];
        float4 Oa[4];
        #pragma unroll
        for (int i = 0; i < 4; ++i) {
            mrow[i] = -1.0e30f; lrow[i] = 0.f;
            Oa[i].x = Oa[i].y = Oa[i].z = Oa[i].w = 0.f;
        }

        const int t0 = max(bq - 2, 0);
        const int t1 = min(bq + 2, SEQ / 64 - 1);

        for (int tt = t0; tt <= t1 + 1; ++tt) {
            const bool gather = (tt == t1 + 1);
            __syncthreads();
            if (!gather) {
                const int jb = tt * 64;
                for (int f = tid; f < 1024; f += 256) {
                    int c = (f < 512) ? f : f - 512;
                    int row = c >> 3, c8 = c & 7;
                    int sect = (f < 512) ? HID : 2 * HID;   // K or V
                    uint4 u = *(const uint4*)(qkv16 + (size_t)(jb + row) * (3 * HID)
                                              + sect + h * HD + c8 * 8);
                    float4 lo4 = make_float4(blo(u.x), bhi(u.x), blo(u.y), bhi(u.y));
                    float4 hi4 = make_float4(blo(u.z), bhi(u.z), blo(u.w), bhi(u.w));
                    if (f < 512) { Ks[row][c8 * 2] = lo4; Ks[row][c8 * 2 + 1] = hi4; }
                    else         { Vs[row][c8 * 2] = lo4; Vs[row][c8 * 2 + 1] = hi4; }
                }
            } else {
                for (int f = tid; f < 512; f += 256) {
                    int c = (f < 256) ? f : f - 256;
                    int row = c >> 3, c8 = c & 7;          // row 0..31 -> key row*64
                    int sect = (f < 256) ? HID : 2 * HID;
                    uint4 u = *(const uint4*)(qkv16 + (size_t)(row << 6) * (3 * HID)
                                              + sect + h * HD + c8 * 8);
                    float4 lo4 = make_float4(blo(u.x), bhi(u.x), blo(u.y), bhi(u.y));
                    float4 hi4 = make_float4(blo(u.z), bhi(u.z), blo(u.w), bhi(u.w));
                    if (f < 256) { Ks[row][c8 * 2] = lo4; Ks[row][c8 * 2 + 1] = hi4; }
                    else         { Vs[row][c8 * 2] = lo4; Vs[row][c8 * 2 + 1] = hi4; }
                }
            }
            __syncthreads();

            // ---- QK^T 4x4 register tile ----
            float s[4][4];
            #pragma unroll
            for (int i = 0; i < 4; ++i)
                #pragma unroll
                for (int j = 0; j < 4; ++j) s[i][j] = 0.f;

            for (int d4 = 0; d4 < 16; ++d4) {
                float4 qv[4], kv[4];
                #pragma unroll
                for (int i = 0; i < 4; ++i) qv[i] = Qs[ty * 4 + i][d4];
                #pragma unroll
                for (int j = 0; j < 4; ++j) kv[j] = Ks[j * 16 + tx][d4];
                #pragma unroll
                for (int i = 0; i < 4; ++i)
                    #pragma unroll
                    for (int j = 0; j < 4; ++j)
                        s[i][j] += qv[i].x * kv[j].x + qv[i].y * kv[j].y
                                 + qv[i].z * kv[j].z + qv[i].w * kv[j].w;
            }

            // ---- mask + scale ----
            #pragma unroll
            for (int i = 0; i < 4; ++i) {
                const int iq = q0 + ty * 4 + i;
                #pragma unroll
                for (int j = 0; j < 4; ++j) {
                    const int c = j * 16 + tx;
                    const int jj = gather ? (c << 6) : (tt * 64 + c);
                    const bool valid = gather ? ((c < 32) && (abs(iq - jj) > WIN))
                                              : (abs(iq - jj) <= WIN);
                    s[i][j] = valid ? s[i][j] * 0.125f : -1.0e30f;
                }
            }

            // ---- online softmax (reduce across tx = low 4 lane bits) ----
            float p[4][4];
            #pragma unroll
            for (int i = 0; i < 4; ++i) {
                float tm = fmaxf(fmaxf(s[i][0], s[i][1]), fmaxf(s[i][2], s[i][3]));
                tm = fmaxf(tm, __shfl_xor(tm, 1));
                tm = fmaxf(tm, __shfl_xor(tm, 2));
                tm = fmaxf(tm, __shfl_xor(tm, 4));
                tm = fmaxf(tm, __shfl_xor(tm, 8));
                const float mn = fmaxf(mrow[i], tm);
                const float alpha = __expf(mrow[i] - mn);
                float ts = 0.f;
                #pragma unroll
                for (int j = 0; j < 4; ++j) {
                    p[i][j] = (s[i][j] > -1.0e29f) ? __expf(s[i][j] - mn) : 0.f;
                    ts += p[i][j];
                }
                ts += __shfl_xor(ts, 1);
                ts += __shfl_xor(ts, 2);
                ts += __shfl_xor(ts, 4);
                ts += __shfl_xor(ts, 8);
                lrow[i] = lrow[i] * alpha + ts;
                mrow[i] = mn;
                Oa[i].x *= alpha; Oa[i].y *= alpha; Oa[i].z *= alpha; Oa[i].w *= alpha;
            }

            // ---- P -> LDS ----
            #pragma unroll
            for (int i = 0; i < 4; ++i)
                #pragma unroll
                for (int j = 0; j < 4; ++j)
                    Ps[(ty * 4 + i) * 68 + j * 16 + tx] = p[i][j];
            __syncthreads();

            // ---- PV ----
            const int nk4 = gather ? 8 : 16;
            for (int k4 = 0; k4 < nk4; ++k4) {
                float4 pr[4];
                #pragma unroll
                for (int i = 0; i < 4; ++i)
                    pr[i] = *(const float4*)&Ps[(ty * 4 + i) * 68 + k4 * 4];
                float4 v0 = Vs[k4 * 4 + 0][tx];
                float4 v1 = Vs[k4 * 4 + 1][tx];
                float4 v2 = Vs[k4 * 4 + 2][tx];
                float4 v3 = Vs[k4 * 4 + 3][tx];
                #pragma unroll
                for (int i = 0; i < 4; ++i) {
                    Oa[i].x += pr[i].x * v0.x + pr[i].y * v1.x + pr[i].z * v2.x + pr[i].w * v3.x;
                    Oa[i].y += pr[i].x * v0.y + pr[i].y * v1.y + pr[i].z * v2.y + pr[i].w * v3.y;
                    Oa[i].z += pr[i].x * v0.z + pr[i].y * v1.z + pr[i].z * v2.z + pr[i].w * v3.z;
                    Oa[i].w += pr[i].x * v0.w + pr[i].y * v1.w + pr[i].z * v2.w + pr[i].w * v3.w;
                }
            }
        }

        // ---- epilogue (skip global rows: q==0) ----
        #pragma unroll
        for (int i = 0; i < 4; ++i) {
            if (ty == 0 && i == 0) continue;
            const int iq = q0 + ty * 4 + i;
            const float inv = 1.0f / lrow[i];
            ushort4 o;
            o.x = bf16b(Oa[i].x * inv);
            o.y = bf16b(Oa[i].y * inv);
            o.z = bf16b(Oa[i].z * inv);
            o.w = bf16b(Oa[i].w * inv);
            *(ushort4*)(aout16 + (size_t)iq * HID + h * HD + tx * 4) = o;
        }
    } else {
        // ----------------- global-row path -----------------
        float*  sc  = (float*)(smem);                        // 8192 B
        float*  red = (float*)(smem + 8192);                 // 1024 B
        float4* q4  = (float4*)(smem + 9216);                // 256 B
        float4 (*ored)[17] = (float4(*)[17])(smem + 9472);   // 4352 B

        const int g = blockIdx.x - 32;
        const int i = g * GSTR;

        if (tid < 8) {
            uint4 u = ((const uint4*)(qkv16 + (size_t)i * (3 * HID) + h * HD))[tid];
            q4[tid * 2]     = make_float4(blo(u.x), bhi(u.x), blo(u.y), bhi(u.y));
            q4[tid * 2 + 1] = make_float4(blo(u.z), bhi(u.z), blo(u.w), bhi(u.w));
        }
        __syncthreads();

        float lmax = -3.0e38f;
        for (int j = tid; j < SEQ; j += 256) {
            const uint4* kp = (const uint4*)(qkv16 + (size_t)j * (3 * HID) + HID + h * HD);
            float s = 0.f;
            #pragma unroll
            for (int c8 = 0; c8 < 8; ++c8) {
                uint4 u = kp[c8];
                float4 qa = q4[c8 * 2];
                float4 qb = q4[c8 * 2 + 1];
                s += qa.x * blo(u.x) + qa.y * bhi(u.x) + qa.z * blo(u.y) + qa.w * bhi(u.y)
                   + qb.x * blo(u.z) + qb.y * bhi(u.z) + qb.z * blo(u.w) + qb.w * bhi(u.w);
            }
            s *= 0.125f;
            sc[j] = s;
            lmax = fmaxf(lmax, s);
        }
        red[tid] = lmax;
        __syncthreads();
        for (int st = 128; st > 0; st >>= 1) {
            if (tid < st) red[tid] = fmaxf(red[tid], red[tid + st]);
            __syncthreads();
        }
        const float mx = red[0];
        __syncthreads();

        float lsum = 0.f;
        for (int j = tid; j < SEQ; j += 256) {
            float e = __expf(sc[j] - mx);
            sc[j] = e;
            lsum += e;
        }
        red[tid] = lsum;
        __syncthreads();
        for (int st = 128; st > 0; st >>= 1) {
            if (tid < st) red[tid] += red[tid + st];
            __syncthreads();
        }
        const float inv = 1.0f / red[0];
        __syncthreads();

        const int d4 = tid & 15;     // dims d4*4 .. d4*4+3
        const int jg = tid >> 4;
        float4 o; o.x = o.y = o.z = o.w = 0.f;
        for (int j = jg; j < SEQ; j += 16) {
            uint2 u = *(const uint2*)(qkv16 + (size_t)j * (3 * HID) + 2 * HID + h * HD + d4 * 4);
            float pv = sc[j];
            o.x += pv * blo(u.x); o.y += pv * bhi(u.x);
            o.z += pv * blo(u.y); o.w += pv * bhi(u.y);
        }
        ored[jg][d4] = o;
        __syncthreads();
        if (tid < 16) {
            float4 acc = ored[0][tid];
            #pragma unroll
            for (int k = 1; k < 16; ++k) {
                float4 t = ored[k][tid];
                acc.x += t.x; acc.y += t.y; acc.z += t.z; acc.w += t.w;
            }
            ushort4 ob;
            ob.x = bf16b(acc.x * inv); ob.y = bf16b(acc.y * inv);
            ob.z = bf16b(acc.z * inv); ob.w = bf16b(acc.w * inv);
            *(ushort4*)(aout16 + (size_t)i * HID + h * HD + tid * 4) = ob;
        }
    }
}

extern "C" void kernel_launch(void* const* d_in, const int* in_sizes, int n_in,
                              void* d_out, int out_size, void* d_ws, size_t ws_size,
                              hipStream_t stream) {
    const float* x    = (const float*)d_in[0];   // [2048,1024] fp32
    const float* Wqkv = (const float*)d_in[1];   // [3072,1024] fp32
    const float* Wout = (const float*)d_in[2];   // [1024,1024] fp32
    float* out = (float*)d_out;                  // [2048,1024] fp32

    // bf16 workspace layout (29.3 MB total)
    unsigned short* x16    = (unsigned short*)d_ws;                 // 2048*1024
    unsigned short* wq16   = x16  + (size_t)SEQ * HID;              // 3072*1024
    unsigned short* wo16   = wq16 + (size_t)3 * HID * HID;          // 1024*1024
    unsigned short* qkv16  = wo16 + (size_t)HID * HID;              // 2048*3072
    unsigned short* aout16 = qkv16 + (size_t)SEQ * 3 * HID;         // 2048*1024

    // 0) fp32 -> bf16 conversions
    cvt_bf16<<<dim3(1024), 256, 0, stream>>>(
        (const float4*)x, (const float4*)Wqkv, (const float4*)Wout,
        (ushort4*)x16, (ushort4*)wq16, (ushort4*)wo16);

    // 1) qkv16 = x16 @ wq16^T  (bf16 out)
    gemm_bt16<unsigned short><<<dim3(3 * HID / 128, SEQ / 128), 256, 0, stream>>>(
        x16, wq16, qkv16, SEQ, 3 * HID, HID);

    // 2) fused banded + global attention (fp32 math, bf16 I/O)
    attn_fused<<<dim3(SEQ / 64 + SEQ / GSTR, NH), 256, 0, stream>>>(qkv16, aout16);

    // 3) out = aout16 @ wo16^T  (fp32 out)
    gemm_bt16<float><<<dim3(HID / 128, SEQ / 128), 256, 0, stream>>>(
        aout16, wo16, out, SEQ, HID, HID);
}

// Round 7
// 204.797 us; speedup vs baseline: 12.2670x; 1.1917x over previous
//
#include <hip/hip_runtime.h>
#include <hip/hip_bf16.h>
#include <math.h>

// Problem constants (B=1)
#define SEQ   2048
#define HID   1024
#define NH    16
#define HD    64
#define WIN   128
#define GSTR  64

typedef __attribute__((ext_vector_type(8))) short short8;   // 8 bf16 = 4 VGPRs
typedef __attribute__((ext_vector_type(4))) float f32x4;    // MFMA C/D
typedef unsigned short ushort_t;

// RNE fp32 -> bf16 bits (finite inputs)
__device__ inline unsigned short bf16b(float f) {
    union { float f; unsigned int u; } v; v.f = f;
    return (unsigned short)((v.u + 0x7FFFu + ((v.u >> 16) & 1u)) >> 16);
}
// bf16 (low/high ushort of a uint) -> fp32
__device__ inline float blo(unsigned int u) {
    union { unsigned int i; float f; } v; v.i = u << 16; return v.f;
}
__device__ inline float bhi(unsigned int u) {
    union { unsigned int i; float f; } v; v.i = u & 0xFFFF0000u; return v.f;
}

#define GLOAD_LDS16(gp, lp)                                                    \
    __builtin_amdgcn_global_load_lds(                                          \
        (const __attribute__((address_space(1))) unsigned int*)(gp),           \
        (__attribute__((address_space(3))) unsigned int*)(lp), 16, 0, 0)

// ---------------------------------------------------------------------------
// fp32 -> bf16 pre-convert of x, Wqkv, Wout
// ---------------------------------------------------------------------------
__global__ __launch_bounds__(256) void cvt_bf16(const float4* __restrict__ x,
                                                const float4* __restrict__ wq,
                                                const float4* __restrict__ wo,
                                                ushort4* __restrict__ x16,
                                                ushort4* __restrict__ wq16,
                                                ushort4* __restrict__ wo16) {
    for (int idx = blockIdx.x * 256 + threadIdx.x; idx < 1572864;
         idx += gridDim.x * 256) {
        const float4* src; ushort4* dst; int off;
        if (idx < 524288)       { src = x;  dst = x16;  off = idx; }
        else if (idx < 1310720) { src = wq; dst = wq16; off = idx - 524288; }
        else                    { src = wo; dst = wo16; off = idx - 1310720; }
        float4 v = src[off];
        ushort4 o;
        o.x = bf16b(v.x); o.y = bf16b(v.y); o.z = bf16b(v.z); o.w = bf16b(v.w);
        dst[off] = o;
    }
}

// ---------------------------------------------------------------------------
// m97-style MFMA GEMM (unchanged from R6): C[M,N] = A[M,K] @ B[N,K]^T
// ---------------------------------------------------------------------------
template <typename OT>
__global__ __launch_bounds__(256) void gemm_bt16(const unsigned short* __restrict__ A,
                                                 const unsigned short* __restrict__ B,
                                                 OT* __restrict__ C,
                                                 int M, int N, int K) {
    __shared__ unsigned short As[128 * 32];
    __shared__ unsigned short Bs[128 * 32];

    const int tid  = threadIdx.x;
    const int wave = tid >> 6;
    const int lane = tid & 63;
    const int quad = lane >> 4;
    const int l15  = lane & 15;
    const int bm = blockIdx.y * 128;
    const int bn = blockIdx.x * 128;
    const int wm = (wave & 1) * 64;
    const int wn = (wave >> 1) * 64;
    const int r0 = wave * 32;
    const int srow = lane >> 2;
    const int scol = (lane & 3) * 8;

    f32x4 acc[4][4];
    #pragma unroll
    for (int i = 0; i < 4; ++i)
        #pragma unroll
        for (int j = 0; j < 4; ++j)
            acc[i][j] = (f32x4){0.f, 0.f, 0.f, 0.f};

    for (int k0 = 0; k0 < K; k0 += 32) {
        #pragma unroll
        for (int t = 0; t < 2; ++t) {
            const int row = r0 + t * 16 + srow;
            GLOAD_LDS16(A + (size_t)(bm + row) * K + k0 + scol,
                        &As[(size_t)row * 32 + scol]);
            GLOAD_LDS16(B + (size_t)(bn + row) * K + k0 + scol,
                        &Bs[(size_t)row * 32 + scol]);
        }
        __syncthreads();

        short8 a[4], b[4];
        #pragma unroll
        for (int im = 0; im < 4; ++im)
            a[im] = *(const short8*)&As[(wm + im * 16 + l15) * 32 + quad * 8];
        #pragma unroll
        for (int jn = 0; jn < 4; ++jn)
            b[jn] = *(const short8*)&Bs[(wn + jn * 16 + l15) * 32 + quad * 8];

        #pragma unroll
        for (int im = 0; im < 4; ++im)
            #pragma unroll
            for (int jn = 0; jn < 4; ++jn)
                acc[im][jn] = __builtin_amdgcn_mfma_f32_16x16x32_bf16(
                    a[im], b[jn], acc[im][jn], 0, 0, 0);
        __syncthreads();
    }

    #pragma unroll
    for (int im = 0; im < 4; ++im)
        #pragma unroll
        for (int jn = 0; jn < 4; ++jn)
            #pragma unroll
            for (int reg = 0; reg < 4; ++reg) {
                const int r = bm + wm + im * 16 + quad * 4 + reg;
                const int c = bn + wn + jn * 16 + l15;
                float v = acc[im][jn][reg];
                if constexpr (sizeof(OT) == 2)
                    C[(size_t)r * N + c] = (OT)bf16b(v);
                else
                    C[(size_t)r * N + c] = (OT)v;
            }
}

// ---------------------------------------------------------------------------
// Fused attention. qkv16: [SEQ][3*HID] bf16; aout16: [SEQ][HID] bf16.
// blockIdx.x < 32: banded+gather flash tile, bf16 MFMA.
//   Wave w owns 16 queries (wq=w*16). Layout convention = gemm_bt16's:
//   A=[m][k] row-major, B=[n][k] row-major, C: col=l15, row=quad*4+reg.
//   QK^T: A=Q[q][d], B=K[j][d].  PV: A=P[q][k], B=V^T[d][k] (V transposed
//   during staging).  Softmax rows are lane-local (quad*4+reg); column
//   reduce via __shfl_xor over l15 bits. Gather tile: 32 global cols; stale
//   LDS beyond col 32 is masked (p=0).
// blockIdx.x >= 32: dense attention for global row i=(bx-32)*64 (VALU).
// ---------------------------------------------------------------------------
__global__ __launch_bounds__(256) void attn_fused(const unsigned short* __restrict__ qkv16,
                                                  unsigned short* __restrict__ aout16) {
    __shared__ __align__(16) unsigned char smem[36864];
    const int tid = threadIdx.x;
    const int h = blockIdx.y;

    if (blockIdx.x < 32) {
        // ----------------- banded path (MFMA) -----------------
        ushort_t* Qs = (ushort_t*)smem;              // [64][72] bf16, 9216 B
        ushort_t* Ks = (ushort_t*)(smem + 9216);     // [64][72]
        ushort_t* Vt = (ushort_t*)(smem + 18432);    // [64][72]  Vt[d][key]
        ushort_t* Ps = (ushort_t*)(smem + 27648);    // [64][72]  Ps[q][key]

        const int bq   = blockIdx.x;
        const int wq   = (tid >> 6) * 16;   // wave's query offset in tile
        const int lane = tid & 63;
        const int quad = lane >> 4;
        const int l15  = lane & 15;
        const int q0   = bq * 64;

        // stage Q tile (64 rows x 8 uint4)
        for (int f = tid; f < 512; f += 256) {
            int row = f >> 3, c8 = f & 7;
            *(uint4*)&Qs[row * 72 + c8 * 8] =
                *(const uint4*)&qkv16[(size_t)(q0 + row) * (3 * HID) + h * HD + c8 * 8];
        }

        int iqr[4];
        float mrow[4], lrow[4];
        f32x4 Oacc[4];
        #pragma unroll
        for (int reg = 0; reg < 4; ++reg) {
            iqr[reg] = q0 + wq + quad * 4 + reg;
            mrow[reg] = -1.0e30f; lrow[reg] = 0.f;
        }
        #pragma unroll
        for (int jt = 0; jt < 4; ++jt) Oacc[jt] = (f32x4){0.f, 0.f, 0.f, 0.f};

        const int t0 = max(bq - 2, 0);
        const int t1 = min(bq + 2, SEQ / 64 - 1);

        for (int tt = t0; tt <= t1 + 1; ++tt) {
            const bool gather = (tt == t1 + 1);
            __syncthreads();
            // ---- stage K rows + V^T cols ----
            const int nf = gather ? 256 : 512;
            for (int f = tid; f < nf; f += 256) {
                int row = f >> 3, c8 = f & 7;          // gather: row 0..31
                const size_t gbase = (size_t)(gather ? (row << 6) : (tt * 64 + row))
                                         * (3 * HID) + h * HD + c8 * 8;
                *(uint4*)&Ks[row * 72 + c8 * 8] = *(const uint4*)&qkv16[gbase + HID];
                uint4 uv = *(const uint4*)&qkv16[gbase + 2 * HID];
                const ushort_t* pv = (const ushort_t*)&uv;
                #pragma unroll
                for (int m2 = 0; m2 < 8; ++m2)
                    Vt[(c8 * 8 + m2) * 72 + row] = pv[m2];
            }
            __syncthreads();

            // ---- QK^T: 4 key-tiles x (K=64 -> 2 mfma) ----
            short8 aq0 = *(const short8*)&Qs[(wq + l15) * 72 + quad * 8];
            short8 aq1 = *(const short8*)&Qs[(wq + l15) * 72 + 32 + quad * 8];
            f32x4 sc4[4];
            #pragma unroll
            for (int kt = 0; kt < 4; ++kt) {
                short8 b0 = *(const short8*)&Ks[(kt * 16 + l15) * 72 + quad * 8];
                short8 b1 = *(const short8*)&Ks[(kt * 16 + l15) * 72 + 32 + quad * 8];
                f32x4 z = (f32x4){0.f, 0.f, 0.f, 0.f};
                z = __builtin_amdgcn_mfma_f32_16x16x32_bf16(aq0, b0, z, 0, 0, 0);
                z = __builtin_amdgcn_mfma_f32_16x16x32_bf16(aq1, b1, z, 0, 0, 0);
                sc4[kt] = z;
            }

            // ---- mask + online softmax (rows = quad*4+reg, cols = kt*16+l15)
            float p[4][4], alpha[4];
            #pragma unroll
            for (int reg = 0; reg < 4; ++reg) {
                float sv[4];
                #pragma unroll
                for (int kt = 0; kt < 4; ++kt) {
                    const int c = kt * 16 + l15;
                    const int j = gather ? (c << 6) : (tt * 64 + c);
                    const bool valid = gather ? ((c < 32) && (abs(iqr[reg] - j) > WIN))
                                              : (abs(iqr[reg] - j) <= WIN);
                    sv[kt] = valid ? sc4[kt][reg] * 0.125f : -1.0e30f;
                }
                float tm = fmaxf(fmaxf(sv[0], sv[1]), fmaxf(sv[2], sv[3]));
                tm = fmaxf(tm, __shfl_xor(tm, 1));
                tm = fmaxf(tm, __shfl_xor(tm, 2));
                tm = fmaxf(tm, __shfl_xor(tm, 4));
                tm = fmaxf(tm, __shfl_xor(tm, 8));
                const float mn = fmaxf(mrow[reg], tm);
                alpha[reg] = __expf(mrow[reg] - mn);
                float ts = 0.f;
                #pragma unroll
                for (int kt = 0; kt < 4; ++kt) {
                    p[kt][reg] = __expf(sv[kt] - mn);
                    ts += p[kt][reg];
                }
                ts += __shfl_xor(ts, 1);
                ts += __shfl_xor(ts, 2);
                ts += __shfl_xor(ts, 4);
                ts += __shfl_xor(ts, 8);
                lrow[reg] = lrow[reg] * alpha[reg] + ts;
                mrow[reg] = mn;
            }

            // ---- P -> LDS (bf16, A-layout rows) + O rescale ----
            #pragma unroll
            for (int kt = 0; kt < 4; ++kt)
                #pragma unroll
                for (int reg = 0; reg < 4; ++reg)
                    Ps[(wq + quad * 4 + reg) * 72 + kt * 16 + l15] = bf16b(p[kt][reg]);
            #pragma unroll
            for (int jt = 0; jt < 4; ++jt)
                #pragma unroll
                for (int reg = 0; reg < 4; ++reg)
                    Oacc[jt][reg] *= alpha[reg];

            // ---- PV: O += P @ V  (A=Ps[q][k], B=Vt[d][k]) ----
            short8 ap0 = *(const short8*)&Ps[(wq + l15) * 72 + quad * 8];
            short8 ap1 = *(const short8*)&Ps[(wq + l15) * 72 + 32 + quad * 8];
            #pragma unroll
            for (int jt = 0; jt < 4; ++jt) {
                short8 bv0 = *(const short8*)&Vt[(jt * 16 + l15) * 72 + quad * 8];
                short8 bv1 = *(const short8*)&Vt[(jt * 16 + l15) * 72 + 32 + quad * 8];
                Oacc[jt] = __builtin_amdgcn_mfma_f32_16x16x32_bf16(ap0, bv0, Oacc[jt], 0, 0, 0);
                Oacc[jt] = __builtin_amdgcn_mfma_f32_16x16x32_bf16(ap1, bv1, Oacc[jt], 0, 0, 0);
            }
        }

        // ---- epilogue: rows = quad*4+reg, dims = jt*16+l15; skip global rows
        #pragma unroll
        for (int reg = 0; reg < 4; ++reg) {
            if (wq + quad * 4 + reg == 0) continue;   // global row (q%64==0)
            const float inv = 1.0f / lrow[reg];
            #pragma unroll
            for (int jt = 0; jt < 4; ++jt)
                aout16[(size_t)iqr[reg] * HID + h * HD + jt * 16 + l15] =
                    bf16b(Oacc[jt][reg] * inv);
        }
    } else {
        // ----------------- global-row path (unchanged R6) -----------------
        float*  sc  = (float*)(smem);                        // 8192 B
        float*  red = (float*)(smem + 8192);                 // 1024 B
        float4* q4  = (float4*)(smem + 9216);                // 256 B
        float4 (*ored)[17] = (float4(*)[17])(smem + 9472);   // 4352 B

        const int g = blockIdx.x - 32;
        const int i = g * GSTR;

        if (tid < 8) {
            uint4 u = ((const uint4*)(qkv16 + (size_t)i * (3 * HID) + h * HD))[tid];
            q4[tid * 2]     = make_float4(blo(u.x), bhi(u.x), blo(u.y), bhi(u.y));
            q4[tid * 2 + 1] = make_float4(blo(u.z), bhi(u.z), blo(u.w), bhi(u.w));
        }
        __syncthreads();

        float lmax = -3.0e38f;
        for (int j = tid; j < SEQ; j += 256) {
            const uint4* kp = (const uint4*)(qkv16 + (size_t)j * (3 * HID) + HID + h * HD);
            float s = 0.f;
            #pragma unroll
            for (int c8 = 0; c8 < 8; ++c8) {
                uint4 u = kp[c8];
                float4 qa = q4[c8 * 2];
                float4 qb = q4[c8 * 2 + 1];
                s += qa.x * blo(u.x) + qa.y * bhi(u.x) + qa.z * blo(u.y) + qa.w * bhi(u.y)
                   + qb.x * blo(u.z) + qb.y * bhi(u.z) + qb.z * blo(u.w) + qb.w * bhi(u.w);
            }
            s *= 0.125f;
            sc[j] = s;
            lmax = fmaxf(lmax, s);
        }
        red[tid] = lmax;
        __syncthreads();
        for (int st = 128; st > 0; st >>= 1) {
            if (tid < st) red[tid] = fmaxf(red[tid], red[tid + st]);
            __syncthreads();
        }
        const float mx = red[0];
        __syncthreads();

        float lsum = 0.f;
        for (int j = tid; j < SEQ; j += 256) {
            float e = __expf(sc[j] - mx);
            sc[j] = e;
            lsum += e;
        }
        red[tid] = lsum;
        __syncthreads();
        for (int st = 128; st > 0; st >>= 1) {
            if (tid < st) red[tid] += red[tid + st];
            __syncthreads();
        }
        const float inv = 1.0f / red[0];
        __syncthreads();

        const int d4 = tid & 15;
        const int jg = tid >> 4;
        float4 o; o.x = o.y = o.z = o.w = 0.f;
        for (int j = jg; j < SEQ; j += 16) {
            uint2 u = *(const uint2*)(qkv16 + (size_t)j * (3 * HID) + 2 * HID + h * HD + d4 * 4);
            float pv = sc[j];
            o.x += pv * blo(u.x); o.y += pv * bhi(u.x);
            o.z += pv * blo(u.y); o.w += pv * bhi(u.y);
        }
        ored[jg][d4] = o;
        __syncthreads();
        if (tid < 16) {
            float4 acc = ored[0][tid];
            #pragma unroll
            for (int k = 1; k < 16; ++k) {
                float4 t = ored[k][tid];
                acc.x += t.x; acc.y += t.y; acc.z += t.z; acc.w += t.w;
            }
            ushort4 ob;
            ob.x = bf16b(acc.x * inv); ob.y = bf16b(acc.y * inv);
            ob.z = bf16b(acc.z * inv); ob.w = bf16b(acc.w * inv);
            *(ushort4*)(aout16 + (size_t)i * HID + h * HD + tid * 4) = ob;
        }
    }
}

extern "C" void kernel_launch(void* const* d_in, const int* in_sizes, int n_in,
                              void* d_out, int out_size, void* d_ws, size_t ws_size,
                              hipStream_t stream) {
    const float* x    = (const float*)d_in[0];   // [2048,1024] fp32
    const float* Wqkv = (const float*)d_in[1];   // [3072,1024] fp32
    const float* Wout = (const float*)d_in[2];   // [1024,1024] fp32
    float* out = (float*)d_out;                  // [2048,1024] fp32

    unsigned short* x16    = (unsigned short*)d_ws;                 // 2048*1024
    unsigned short* wq16   = x16  + (size_t)SEQ * HID;              // 3072*1024
    unsigned short* wo16   = wq16 + (size_t)3 * HID * HID;          // 1024*1024
    unsigned short* qkv16  = wo16 + (size_t)HID * HID;              // 2048*3072
    unsigned short* aout16 = qkv16 + (size_t)SEQ * 3 * HID;         // 2048*1024

    // 0) fp32 -> bf16 conversions
    cvt_bf16<<<dim3(1024), 256, 0, stream>>>(
        (const float4*)x, (const float4*)Wqkv, (const float4*)Wout,
        (ushort4*)x16, (ushort4*)wq16, (ushort4*)wo16);

    // 1) qkv16 = x16 @ wq16^T  (bf16 out)
    gemm_bt16<unsigned short><<<dim3(3 * HID / 128, SEQ / 128), 256, 0, stream>>>(
        x16, wq16, qkv16, SEQ, 3 * HID, HID);

    // 2) fused banded (MFMA) + global attention
    attn_fused<<<dim3(SEQ / 64 + SEQ / GSTR, NH), 256, 0, stream>>>(qkv16, aout16);

    // 3) out = aout16 @ wo16^T  (fp32 out)
    gemm_bt16<float><<<dim3(HID / 128, SEQ / 128), 256, 0, stream>>>(
        aout16, wo16, out, SEQ, HID, HID);
}

// Round 8
// 199.990 us; speedup vs baseline: 12.5618x; 1.0240x over previous
//
#include <hip/hip_runtime.h>
#include <hip/hip_bf16.h>
#include <math.h>

// Problem constants (B=1)
#define SEQ   2048
#define HID   1024
#define NH    16
#define HD    64
#define WIN   128
#define GSTR  64

typedef __attribute__((ext_vector_type(8))) short short8;   // 8 bf16 = 4 VGPRs
typedef __attribute__((ext_vector_type(4))) float f32x4;    // MFMA C/D
typedef unsigned short ushort_t;

// RNE fp32 -> bf16 bits (finite inputs)
__device__ inline unsigned short bf16b(float f) {
    union { float f; unsigned int u; } v; v.f = f;
    return (unsigned short)((v.u + 0x7FFFu + ((v.u >> 16) & 1u)) >> 16);
}
// bf16 (low/high ushort of a uint) -> fp32
__device__ inline float blo(unsigned int u) {
    union { unsigned int i; float f; } v; v.i = u << 16; return v.f;
}
__device__ inline float bhi(unsigned int u) {
    union { unsigned int i; float f; } v; v.i = u & 0xFFFF0000u; return v.f;
}

#define GLOAD_LDS16(gp, lp)                                                    \
    __builtin_amdgcn_global_load_lds(                                          \
        (const __attribute__((address_space(1))) unsigned int*)(gp),           \
        (__attribute__((address_space(3))) unsigned int*)(lp), 16, 0, 0)

// ---------------------------------------------------------------------------
// fp32 -> bf16 pre-convert of x, Wqkv, Wout
// ---------------------------------------------------------------------------
__global__ __launch_bounds__(256) void cvt_bf16(const float4* __restrict__ x,
                                                const float4* __restrict__ wq,
                                                const float4* __restrict__ wo,
                                                ushort4* __restrict__ x16,
                                                ushort4* __restrict__ wq16,
                                                ushort4* __restrict__ wo16) {
    for (int idx = blockIdx.x * 256 + threadIdx.x; idx < 1572864;
         idx += gridDim.x * 256) {
        const float4* src; ushort4* dst; int off;
        if (idx < 524288)       { src = x;  dst = x16;  off = idx; }
        else if (idx < 1310720) { src = wq; dst = wq16; off = idx - 524288; }
        else                    { src = wo; dst = wo16; off = idx - 1310720; }
        float4 v = src[off];
        ushort4 o;
        o.x = bf16b(v.x); o.y = bf16b(v.y); o.z = bf16b(v.z); o.w = bf16b(v.w);
        dst[off] = o;
    }
}

// ---------------------------------------------------------------------------
// m97-style MFMA GEMM: C[M,N] = A[M,K] @ B[N,K]^T, bf16 in, fp32 acc.
// Tile 128 x BN (BN = 128 or 64), BK=32, 256 threads (4 waves).
// ---------------------------------------------------------------------------
template <int BN, typename OT>
__global__ __launch_bounds__(256) void gemm_bt16(const unsigned short* __restrict__ A,
                                                 const unsigned short* __restrict__ B,
                                                 OT* __restrict__ C,
                                                 int M, int N, int K) {
    constexpr int NJ = BN / 32;            // n-frags per wave (4 or 2)
    __shared__ unsigned short As[128 * 32];
    __shared__ unsigned short Bs[BN * 32];

    const int tid  = threadIdx.x;
    const int wave = tid >> 6;
    const int lane = tid & 63;
    const int quad = lane >> 4;
    const int l15  = lane & 15;
    const int bm = blockIdx.y * 128;
    const int bn = blockIdx.x * BN;
    const int wm = (wave & 1) * 64;
    const int wn = (wave >> 1) * (BN / 2);
    const int srow = lane >> 2;
    const int scol = (lane & 3) * 8;

    f32x4 acc[4][NJ];
    #pragma unroll
    for (int i = 0; i < 4; ++i)
        #pragma unroll
        for (int j = 0; j < NJ; ++j)
            acc[i][j] = (f32x4){0.f, 0.f, 0.f, 0.f};

    for (int k0 = 0; k0 < K; k0 += 32) {
        #pragma unroll
        for (int t = 0; t < 2; ++t) {
            const int row = wave * 32 + t * 16 + srow;
            GLOAD_LDS16(A + (size_t)(bm + row) * K + k0 + scol,
                        &As[(size_t)row * 32 + scol]);
        }
        #pragma unroll
        for (int t = 0; t < BN / 64; ++t) {
            const int row = wave * (BN / 4) + t * 16 + srow;
            GLOAD_LDS16(B + (size_t)(bn + row) * K + k0 + scol,
                        &Bs[(size_t)row * 32 + scol]);
        }
        __syncthreads();

        short8 a[4], b[NJ];
        #pragma unroll
        for (int im = 0; im < 4; ++im)
            a[im] = *(const short8*)&As[(wm + im * 16 + l15) * 32 + quad * 8];
        #pragma unroll
        for (int jn = 0; jn < NJ; ++jn)
            b[jn] = *(const short8*)&Bs[(wn + jn * 16 + l15) * 32 + quad * 8];

        #pragma unroll
        for (int im = 0; im < 4; ++im)
            #pragma unroll
            for (int jn = 0; jn < NJ; ++jn)
                acc[im][jn] = __builtin_amdgcn_mfma_f32_16x16x32_bf16(
                    a[im], b[jn], acc[im][jn], 0, 0, 0);
        __syncthreads();
    }

    #pragma unroll
    for (int im = 0; im < 4; ++im)
        #pragma unroll
        for (int jn = 0; jn < NJ; ++jn)
            #pragma unroll
            for (int reg = 0; reg < 4; ++reg) {
                const int r = bm + wm + im * 16 + quad * 4 + reg;
                const int c = bn + wn + jn * 16 + l15;
                float v = acc[im][jn][reg];
                if constexpr (sizeof(OT) == 2)
                    C[(size_t)r * N + c] = (OT)bf16b(v);
                else
                    C[(size_t)r * N + c] = (OT)v;
            }
}

// ---------------------------------------------------------------------------
// Fused attention. qkv16: [SEQ][3*HID] bf16; aout16: [SEQ][HID] bf16.
// blockIdx.x < 32: banded+gather flash tile, bf16 MFMA, S^T orientation:
//   S^T = MFMA(A=K, B=Q): C rows = key (quad*4+reg), cols = query (l15).
//   Each lane owns ONE query (qi = q0 + wave*16 + l15): softmax row state is
//   lane-scalar; reduce = 16 in-lane + shfl_xor(16,32) over quads.
//   P packed to LDS as ushort4 (row q, conflict-free); PV: O^T = MFMA(A=V^T,
//   B=P): rows = d, cols = query. Epilogue: 4x ushort4 per lane.
//   V^T staged via key-pair dword writes (8-way worst case).
// blockIdx.x >= 32: dense attention for global row i=(bx-32)*64 (VALU).
// ---------------------------------------------------------------------------
__global__ __launch_bounds__(256) void attn_fused(const unsigned short* __restrict__ qkv16,
                                                  unsigned short* __restrict__ aout16) {
    __shared__ __align__(16) unsigned char smem[36864];
    const int tid = threadIdx.x;
    const int h = blockIdx.y;

    if (blockIdx.x < 32) {
        // ----------------- banded path (S^T MFMA) -----------------
        ushort_t* Qs = (ushort_t*)smem;              // [64][72] bf16, 9216 B
        ushort_t* Ks = (ushort_t*)(smem + 9216);     // [64][72]
        ushort_t* Vt = (ushort_t*)(smem + 18432);    // [64][72]  Vt[d][key]
        ushort_t* Ps = (ushort_t*)(smem + 27648);    // [64][72]  Ps[q][key]

        const int bq   = blockIdx.x;
        const int w    = tid >> 6;
        const int lane = tid & 63;
        const int quad = lane >> 4;
        const int l15  = lane & 15;
        const int q0   = bq * 64;
        const int qi   = q0 + w * 16 + l15;   // this lane's query

        // stage Q tile (64 rows x 8 uint4)
        for (int f = tid; f < 512; f += 256) {
            int row = f >> 3, c8 = f & 7;
            *(uint4*)&Qs[row * 72 + c8 * 8] =
                *(const uint4*)&qkv16[(size_t)(q0 + row) * (3 * HID) + h * HD + c8 * 8];
        }

        float mq = -1.0e30f, lq = 0.f;
        f32x4 Oacc[4];
        #pragma unroll
        for (int jt = 0; jt < 4; ++jt) Oacc[jt] = (f32x4){0.f, 0.f, 0.f, 0.f};

        const int t0 = max(bq - 2, 0);
        const int t1 = min(bq + 2, SEQ / 64 - 1);

        for (int tt = t0; tt <= t1 + 1; ++tt) {
            const bool gather = (tt == t1 + 1);
            __syncthreads();
            // ---- stage K rows (vector) ----
            const int nfk = gather ? 256 : 512;
            for (int f = tid; f < nfk; f += 256) {
                int row = f >> 3, c8 = f & 7;
                const size_t gb = (size_t)(gather ? (row << 6) : (tt * 64 + row))
                                      * (3 * HID) + HID + h * HD + c8 * 8;
                *(uint4*)&Ks[row * 72 + c8 * 8] = *(const uint4*)&qkv16[gb];
            }
            // ---- stage V^T via key pairs (dword writes) ----
            const int nfv = gather ? 256 : 512;
            for (int f = tid; f < nfv; f += 256) {
                int kp = f >> 4;            // key pair (window 0..31, gather 0..15)
                int dc = f & 15;            // 4-dim chunk
                const int k0i = 2 * kp, k1i = 2 * kp + 1;
                const size_t b0 = (size_t)(gather ? (k0i << 6) : (tt * 64 + k0i))
                                      * (3 * HID) + 2 * HID + h * HD + dc * 4;
                const size_t b1 = (size_t)(gather ? (k1i << 6) : (tt * 64 + k1i))
                                      * (3 * HID) + 2 * HID + h * HD + dc * 4;
                uint2 va = *(const uint2*)&qkv16[b0];
                uint2 vb = *(const uint2*)&qkv16[b1];
                unsigned int w0 = (va.x & 0xFFFFu) | (vb.x << 16);
                unsigned int w1 = (va.x >> 16)     | (vb.x & 0xFFFF0000u);
                unsigned int w2 = (va.y & 0xFFFFu) | (vb.y << 16);
                unsigned int w3 = (va.y >> 16)     | (vb.y & 0xFFFF0000u);
                *(unsigned int*)&Vt[(dc * 4 + 0) * 72 + 2 * kp] = w0;
                *(unsigned int*)&Vt[(dc * 4 + 1) * 72 + 2 * kp] = w1;
                *(unsigned int*)&Vt[(dc * 4 + 2) * 72 + 2 * kp] = w2;
                *(unsigned int*)&Vt[(dc * 4 + 3) * 72 + 2 * kp] = w3;
            }
            __syncthreads();

            // ---- S^T = K @ Q^T : 4 key-chunks ----
            short8 bQ0 = *(const short8*)&Qs[(w * 16 + l15) * 72 + quad * 8];
            short8 bQ1 = *(const short8*)&Qs[(w * 16 + l15) * 72 + 32 + quad * 8];
            f32x4 st[4];
            #pragma unroll
            for (int kt = 0; kt < 4; ++kt) {
                short8 aK0 = *(const short8*)&Ks[(kt * 16 + l15) * 72 + quad * 8];
                short8 aK1 = *(const short8*)&Ks[(kt * 16 + l15) * 72 + 32 + quad * 8];
                f32x4 z = (f32x4){0.f, 0.f, 0.f, 0.f};
                z = __builtin_amdgcn_mfma_f32_16x16x32_bf16(aK0, bQ0, z, 0, 0, 0);
                z = __builtin_amdgcn_mfma_f32_16x16x32_bf16(aK1, bQ1, z, 0, 0, 0);
                st[kt] = z;
            }

            // ---- mask + scale (key = kt*16 + quad*4 + reg, query = qi) ----
            float sv[4][4];
            float tm = -1.0e30f;
            #pragma unroll
            for (int kt = 0; kt < 4; ++kt)
                #pragma unroll
                for (int reg = 0; reg < 4; ++reg) {
                    const int c = kt * 16 + quad * 4 + reg;
                    const int j = gather ? (c << 6) : (tt * 64 + c);
                    const bool valid = gather ? ((c < 32) && (abs(qi - j) > WIN))
                                              : (abs(qi - j) <= WIN);
                    sv[kt][reg] = valid ? st[kt][reg] * 0.125f : -1.0e30f;
                    tm = fmaxf(tm, sv[kt][reg]);
                }

            // ---- online softmax: reduce over quads only ----
            tm = fmaxf(tm, __shfl_xor(tm, 16));
            tm = fmaxf(tm, __shfl_xor(tm, 32));
            const float mn = fmaxf(mq, tm);
            const float alpha = __expf(mq - mn);
            float p[4][4];
            float ts = 0.f;
            #pragma unroll
            for (int kt = 0; kt < 4; ++kt)
                #pragma unroll
                for (int reg = 0; reg < 4; ++reg) {
                    p[kt][reg] = __expf(sv[kt][reg] - mn);
                    ts += p[kt][reg];
                }
            ts += __shfl_xor(ts, 16);
            ts += __shfl_xor(ts, 32);
            lq = lq * alpha + ts;
            mq = mn;

            // ---- P -> LDS packed (row q, keys kt*16+quad*4 .. +3) ----
            #pragma unroll
            for (int kt = 0; kt < 4; ++kt) {
                ushort4 pk;
                pk.x = bf16b(p[kt][0]); pk.y = bf16b(p[kt][1]);
                pk.z = bf16b(p[kt][2]); pk.w = bf16b(p[kt][3]);
                *(ushort4*)&Ps[(w * 16 + l15) * 72 + kt * 16 + quad * 4] = pk;
            }
            #pragma unroll
            for (int jt = 0; jt < 4; ++jt) {
                Oacc[jt][0] *= alpha; Oacc[jt][1] *= alpha;
                Oacc[jt][2] *= alpha; Oacc[jt][3] *= alpha;
            }

            // ---- O^T += V^T @ P^T  (A=Vt[d][key], B=Ps[q][key]) ----
            short8 bP0 = *(const short8*)&Ps[(w * 16 + l15) * 72 + quad * 8];
            short8 bP1 = *(const short8*)&Ps[(w * 16 + l15) * 72 + 32 + quad * 8];
            #pragma unroll
            for (int jt = 0; jt < 4; ++jt) {
                short8 aV0 = *(const short8*)&Vt[(jt * 16 + l15) * 72 + quad * 8];
                short8 aV1 = *(const short8*)&Vt[(jt * 16 + l15) * 72 + 32 + quad * 8];
                Oacc[jt] = __builtin_amdgcn_mfma_f32_16x16x32_bf16(aV0, bP0, Oacc[jt], 0, 0, 0);
                Oacc[jt] = __builtin_amdgcn_mfma_f32_16x16x32_bf16(aV1, bP1, Oacc[jt], 0, 0, 0);
            }
        }

        // ---- epilogue: lane owns query qi; d = jt*16 + quad*4 + reg ----
        if (!(w == 0 && l15 == 0)) {   // skip global rows (qi % 64 == 0)
            const float inv = 1.0f / lq;
            #pragma unroll
            for (int jt = 0; jt < 4; ++jt) {
                ushort4 o;
                o.x = bf16b(Oacc[jt][0] * inv);
                o.y = bf16b(Oacc[jt][1] * inv);
                o.z = bf16b(Oacc[jt][2] * inv);
                o.w = bf16b(Oacc[jt][3] * inv);
                *(ushort4*)&aout16[(size_t)qi * HID + h * HD + jt * 16 + quad * 4] = o;
            }
        }
    } else {
        // ----------------- global-row path (unchanged) -----------------
        float*  sc  = (float*)(smem);                        // 8192 B
        float*  red = (float*)(smem + 8192);                 // 1024 B
        float4* q4  = (float4*)(smem + 9216);                // 256 B
        float4 (*ored)[17] = (float4(*)[17])(smem + 9472);   // 4352 B

        const int g = blockIdx.x - 32;
        const int i = g * GSTR;

        if (tid < 8) {
            uint4 u = ((const uint4*)(qkv16 + (size_t)i * (3 * HID) + h * HD))[tid];
            q4[tid * 2]     = make_float4(blo(u.x), bhi(u.x), blo(u.y), bhi(u.y));
            q4[tid * 2 + 1] = make_float4(blo(u.z), bhi(u.z), blo(u.w), bhi(u.w));
        }
        __syncthreads();

        float lmax = -3.0e38f;
        for (int j = tid; j < SEQ; j += 256) {
            const uint4* kp = (const uint4*)(qkv16 + (size_t)j * (3 * HID) + HID + h * HD);
            float s = 0.f;
            #pragma unroll
            for (int c8 = 0; c8 < 8; ++c8) {
                uint4 u = kp[c8];
                float4 qa = q4[c8 * 2];
                float4 qb = q4[c8 * 2 + 1];
                s += qa.x * blo(u.x) + qa.y * bhi(u.x) + qa.z * blo(u.y) + qa.w * bhi(u.y)
                   + qb.x * blo(u.z) + qb.y * bhi(u.z) + qb.z * blo(u.w) + qb.w * bhi(u.w);
            }
            s *= 0.125f;
            sc[j] = s;
            lmax = fmaxf(lmax, s);
        }
        red[tid] = lmax;
        __syncthreads();
        for (int st = 128; st > 0; st >>= 1) {
            if (tid < st) red[tid] = fmaxf(red[tid], red[tid + st]);
            __syncthreads();
        }
        const float mx = red[0];
        __syncthreads();

        float lsum = 0.f;
        for (int j = tid; j < SEQ; j += 256) {
            float e = __expf(sc[j] - mx);
            sc[j] = e;
            lsum += e;
        }
        red[tid] = lsum;
        __syncthreads();
        for (int st = 128; st > 0; st >>= 1) {
            if (tid < st) red[tid] += red[tid + st];
            __syncthreads();
        }
        const float inv = 1.0f / red[0];
        __syncthreads();

        const int d4 = tid & 15;
        const int jg = tid >> 4;
        float4 o; o.x = o.y = o.z = o.w = 0.f;
        for (int j = jg; j < SEQ; j += 16) {
            uint2 u = *(const uint2*)(qkv16 + (size_t)j * (3 * HID) + 2 * HID + h * HD + d4 * 4);
            float pv = sc[j];
            o.x += pv * blo(u.x); o.y += pv * bhi(u.x);
            o.z += pv * blo(u.y); o.w += pv * bhi(u.y);
        }
        ored[jg][d4] = o;
        __syncthreads();
        if (tid < 16) {
            float4 acc = ored[0][tid];
            #pragma unroll
            for (int k = 1; k < 16; ++k) {
                float4 t = ored[k][tid];
                acc.x += t.x; acc.y += t.y; acc.z += t.z; acc.w += t.w;
            }
            ushort4 ob;
            ob.x = bf16b(acc.x * inv); ob.y = bf16b(acc.y * inv);
            ob.z = bf16b(acc.z * inv); ob.w = bf16b(acc.w * inv);
            *(ushort4*)(aout16 + (size_t)i * HID + h * HD + tid * 4) = ob;
        }
    }
}

extern "C" void kernel_launch(void* const* d_in, const int* in_sizes, int n_in,
                              void* d_out, int out_size, void* d_ws, size_t ws_size,
                              hipStream_t stream) {
    const float* x    = (const float*)d_in[0];   // [2048,1024] fp32
    const float* Wqkv = (const float*)d_in[1];   // [3072,1024] fp32
    const float* Wout = (const float*)d_in[2];   // [1024,1024] fp32
    float* out = (float*)d_out;                  // [2048,1024] fp32

    unsigned short* x16    = (unsigned short*)d_ws;                 // 2048*1024
    unsigned short* wq16   = x16  + (size_t)SEQ * HID;              // 3072*1024
    unsigned short* wo16   = wq16 + (size_t)3 * HID * HID;          // 1024*1024
    unsigned short* qkv16  = wo16 + (size_t)HID * HID;              // 2048*3072
    unsigned short* aout16 = qkv16 + (size_t)SEQ * 3 * HID;         // 2048*1024

    // 0) fp32 -> bf16 conversions
    cvt_bf16<<<dim3(1024), 256, 0, stream>>>(
        (const float4*)x, (const float4*)Wqkv, (const float4*)Wout,
        (ushort4*)x16, (ushort4*)wq16, (ushort4*)wo16);

    // 1) qkv16 = x16 @ wq16^T  (bf16 out)
    gemm_bt16<128, unsigned short><<<dim3(3 * HID / 128, SEQ / 128), 256, 0, stream>>>(
        x16, wq16, qkv16, SEQ, 3 * HID, HID);

    // 2) fused banded (S^T MFMA) + global attention
    attn_fused<<<dim3(SEQ / 64 + SEQ / GSTR, NH), 256, 0, stream>>>(qkv16, aout16);

    // 3) out = aout16 @ wo16^T  (fp32 out), BN=64 -> 256 blocks
    gemm_bt16<64, float><<<dim3(HID / 64, SEQ / 128), 256, 0, stream>>>(
        aout16, wo16, out, SEQ, HID, HID);
}

// Round 9
// 159.081 us; speedup vs baseline: 15.7923x; 1.2572x over previous
//
#include <hip/hip_runtime.h>
#include <hip/hip_bf16.h>
#include <math.h>

// Problem constants (B=1)
#define SEQ   2048
#define HID   1024
#define NH    16
#define HD    64
#define WIN   128
#define GSTR  64

typedef __attribute__((ext_vector_type(8))) short short8;   // 8 bf16 = 4 VGPRs
typedef __attribute__((ext_vector_type(4))) float f32x4;    // MFMA C/D
typedef unsigned short ushort_t;

// RNE fp32 -> bf16 bits (finite inputs)
__device__ inline unsigned short bf16b(float f) {
    union { float f; unsigned int u; } v; v.f = f;
    return (unsigned short)((v.u + 0x7FFFu + ((v.u >> 16) & 1u)) >> 16);
}
// bf16 (low/high ushort of a uint) -> fp32
__device__ inline float blo(unsigned int u) {
    union { unsigned int i; float f; } v; v.i = u << 16; return v.f;
}
__device__ inline float bhi(unsigned int u) {
    union { unsigned int i; float f; } v; v.i = u & 0xFFFF0000u; return v.f;
}

#define GLOAD_LDS16(gp, lp)                                                    \
    __builtin_amdgcn_global_load_lds(                                          \
        (const __attribute__((address_space(1))) unsigned int*)(gp),           \
        (__attribute__((address_space(3))) unsigned int*)(lp), 16, 0, 0)

// ---------------------------------------------------------------------------
// fp32 -> bf16 pre-convert of x, Wqkv, Wout
// ---------------------------------------------------------------------------
__global__ __launch_bounds__(256) void cvt_bf16(const float4* __restrict__ x,
                                                const float4* __restrict__ wq,
                                                const float4* __restrict__ wo,
                                                ushort4* __restrict__ x16,
                                                ushort4* __restrict__ wq16,
                                                ushort4* __restrict__ wo16) {
    for (int idx = blockIdx.x * 256 + threadIdx.x; idx < 1572864;
         idx += gridDim.x * 256) {
        const float4* src; ushort4* dst; int off;
        if (idx < 524288)       { src = x;  dst = x16;  off = idx; }
        else if (idx < 1310720) { src = wq; dst = wq16; off = idx - 524288; }
        else                    { src = wo; dst = wo16; off = idx - 1310720; }
        float4 v = src[off];
        ushort4 o;
        o.x = bf16b(v.x); o.y = bf16b(v.y); o.z = bf16b(v.z); o.w = bf16b(v.w);
        dst[off] = o;
    }
}

// ---------------------------------------------------------------------------
// m97-style MFMA GEMM: C[M,N] = A[M,K] @ B[N,K]^T, bf16 in, fp32 acc.
// Tile 128 x BN (BN = 128 or 64), BK=32, 256 threads (4 waves).
// ---------------------------------------------------------------------------
template <int BN, typename OT>
__global__ __launch_bounds__(256) void gemm_bt16(const unsigned short* __restrict__ A,
                                                 const unsigned short* __restrict__ B,
                                                 OT* __restrict__ C,
                                                 int M, int N, int K) {
    constexpr int NJ = BN / 32;
    __shared__ unsigned short As[128 * 32];
    __shared__ unsigned short Bs[BN * 32];

    const int tid  = threadIdx.x;
    const int wave = tid >> 6;
    const int lane = tid & 63;
    const int quad = lane >> 4;
    const int l15  = lane & 15;
    const int bm = blockIdx.y * 128;
    const int bn = blockIdx.x * BN;
    const int wm = (wave & 1) * 64;
    const int wn = (wave >> 1) * (BN / 2);
    const int srow = lane >> 2;
    const int scol = (lane & 3) * 8;

    f32x4 acc[4][NJ];
    #pragma unroll
    for (int i = 0; i < 4; ++i)
        #pragma unroll
        for (int j = 0; j < NJ; ++j)
            acc[i][j] = (f32x4){0.f, 0.f, 0.f, 0.f};

    for (int k0 = 0; k0 < K; k0 += 32) {
        #pragma unroll
        for (int t = 0; t < 2; ++t) {
            const int row = wave * 32 + t * 16 + srow;
            GLOAD_LDS16(A + (size_t)(bm + row) * K + k0 + scol,
                        &As[(size_t)row * 32 + scol]);
        }
        #pragma unroll
        for (int t = 0; t < BN / 64; ++t) {
            const int row = wave * (BN / 4) + t * 16 + srow;
            GLOAD_LDS16(B + (size_t)(bn + row) * K + k0 + scol,
                        &Bs[(size_t)row * 32 + scol]);
        }
        __syncthreads();

        short8 a[4], b[NJ];
        #pragma unroll
        for (int im = 0; im < 4; ++im)
            a[im] = *(const short8*)&As[(wm + im * 16 + l15) * 32 + quad * 8];
        #pragma unroll
        for (int jn = 0; jn < NJ; ++jn)
            b[jn] = *(const short8*)&Bs[(wn + jn * 16 + l15) * 32 + quad * 8];

        #pragma unroll
        for (int im = 0; im < 4; ++im)
            #pragma unroll
            for (int jn = 0; jn < NJ; ++jn)
                acc[im][jn] = __builtin_amdgcn_mfma_f32_16x16x32_bf16(
                    a[im], b[jn], acc[im][jn], 0, 0, 0);
        __syncthreads();
    }

    #pragma unroll
    for (int im = 0; im < 4; ++im)
        #pragma unroll
        for (int jn = 0; jn < NJ; ++jn)
            #pragma unroll
            for (int reg = 0; reg < 4; ++reg) {
                const int r = bm + wm + im * 16 + quad * 4 + reg;
                const int c = bn + wn + jn * 16 + l15;
                float v = acc[im][jn][reg];
                if constexpr (sizeof(OT) == 2)
                    C[(size_t)r * N + c] = (OT)bf16b(v);
                else
                    C[(size_t)r * N + c] = (OT)v;
            }
}

// ---------------------------------------------------------------------------
// Fused attention. qkv16: [SEQ][3*HID] bf16; aout16: [SEQ][HID] bf16.
// blockIdx.x < 32: banded+gather flash tile (S^T MFMA, as R8) with register
//   prefetch of the next K/V tile overlapping compute.
// blockIdx.x in {32,33}: global rows, MFMA flash-decoding: 16 global queries
//   (gh*16..+15 -> rows (gh*16+t)*64), 4 waves each scanning 512 keys in 16
//   tiles of 32 with wave-private LDS (no intra-loop barriers), final 4-way
//   (m,l,O) merge via LDS.
// ---------------------------------------------------------------------------
__global__ __launch_bounds__(256) void attn_fused(const unsigned short* __restrict__ qkv16,
                                                  unsigned short* __restrict__ aout16) {
    __shared__ __align__(16) unsigned char smem[38912];
    const int tid = threadIdx.x;
    const int h = blockIdx.y;
    const int w    = tid >> 6;
    const int lane = tid & 63;
    const int quad = lane >> 4;
    const int l15  = lane & 15;

    if (blockIdx.x < 32) {
        // ----------------- banded path (S^T MFMA + prefetch) -----------------
        ushort_t* Qs = (ushort_t*)smem;              // [64][72] bf16, 9216 B
        ushort_t* Ks = (ushort_t*)(smem + 9216);     // [64][72]
        ushort_t* Vt = (ushort_t*)(smem + 18432);    // [64][72]  Vt[d][key]
        ushort_t* Ps = (ushort_t*)(smem + 27648);    // [64][72]  Ps[q][key]

        const int bq = blockIdx.x;
        const int q0 = bq * 64;
        const int qi = q0 + w * 16 + l15;   // this lane's query

        // stage Q tile
        for (int f = tid; f < 512; f += 256) {
            int row = f >> 3, c8 = f & 7;
            *(uint4*)&Qs[row * 72 + c8 * 8] =
                *(const uint4*)&qkv16[(size_t)(q0 + row) * (3 * HID) + h * HD + c8 * 8];
        }

        float mq = -1.0e30f, lq = 0.f;
        f32x4 Oacc[4];
        #pragma unroll
        for (int jt = 0; jt < 4; ++jt) Oacc[jt] = (f32x4){0.f, 0.f, 0.f, 0.f};

        const int t0 = max(bq - 2, 0);
        const int t1 = min(bq + 2, SEQ / 64 - 1);

        uint4 pk[2];
        uint2 pva[2], pvb[2];

        // prefetch helper (inlined twice): loads tile (tt2) into regs
        auto prefetch = [&](int tt2, bool g2) {
            const int nf = g2 ? 256 : 512;
            #pragma unroll
            for (int u = 0; u < 2; ++u) {
                const int f = tid + u * 256;
                if (f < nf) {
                    const int row = f >> 3, c8 = f & 7;
                    const size_t gb = (size_t)(g2 ? (row << 6) : (tt2 * 64 + row))
                                          * (3 * HID) + HID + h * HD + c8 * 8;
                    pk[u] = *(const uint4*)&qkv16[gb];
                    const int kp = f >> 4, dc = f & 15;
                    const int k0i = 2 * kp, k1i = 2 * kp + 1;
                    const size_t b0 = (size_t)(g2 ? (k0i << 6) : (tt2 * 64 + k0i))
                                          * (3 * HID) + 2 * HID + h * HD + dc * 4;
                    const size_t b1 = (size_t)(g2 ? (k1i << 6) : (tt2 * 64 + k1i))
                                          * (3 * HID) + 2 * HID + h * HD + dc * 4;
                    pva[u] = *(const uint2*)&qkv16[b0];
                    pvb[u] = *(const uint2*)&qkv16[b1];
                }
            }
        };
        // commit helper: regs -> LDS
        auto commit = [&](bool g2) {
            const int nf = g2 ? 256 : 512;
            #pragma unroll
            for (int u = 0; u < 2; ++u) {
                const int f = tid + u * 256;
                if (f < nf) {
                    const int row = f >> 3, c8 = f & 7;
                    *(uint4*)&Ks[row * 72 + c8 * 8] = pk[u];
                    const int kp = f >> 4, dc = f & 15;
                    uint2 va = pva[u], vb = pvb[u];
                    unsigned int w0 = (va.x & 0xFFFFu) | (vb.x << 16);
                    unsigned int w1 = (va.x >> 16)     | (vb.x & 0xFFFF0000u);
                    unsigned int w2 = (va.y & 0xFFFFu) | (vb.y << 16);
                    unsigned int w3 = (va.y >> 16)     | (vb.y & 0xFFFF0000u);
                    *(unsigned int*)&Vt[(dc * 4 + 0) * 72 + 2 * kp] = w0;
                    *(unsigned int*)&Vt[(dc * 4 + 1) * 72 + 2 * kp] = w1;
                    *(unsigned int*)&Vt[(dc * 4 + 2) * 72 + 2 * kp] = w2;
                    *(unsigned int*)&Vt[(dc * 4 + 3) * 72 + 2 * kp] = w3;
                }
            }
        };

        prefetch(t0, false);
        commit(false);
        __syncthreads();

        for (int tt = t0; tt <= t1 + 1; ++tt) {
            const bool gather = (tt == t1 + 1);
            const bool hasnext = (tt < t1 + 1);
            if (hasnext) prefetch(tt + 1, (tt + 1) == t1 + 1);

            // ---- S^T = K @ Q^T ----
            short8 bQ0 = *(const short8*)&Qs[(w * 16 + l15) * 72 + quad * 8];
            short8 bQ1 = *(const short8*)&Qs[(w * 16 + l15) * 72 + 32 + quad * 8];
            f32x4 st[4];
            #pragma unroll
            for (int kt = 0; kt < 4; ++kt) {
                short8 aK0 = *(const short8*)&Ks[(kt * 16 + l15) * 72 + quad * 8];
                short8 aK1 = *(const short8*)&Ks[(kt * 16 + l15) * 72 + 32 + quad * 8];
                f32x4 z = (f32x4){0.f, 0.f, 0.f, 0.f};
                z = __builtin_amdgcn_mfma_f32_16x16x32_bf16(aK0, bQ0, z, 0, 0, 0);
                z = __builtin_amdgcn_mfma_f32_16x16x32_bf16(aK1, bQ1, z, 0, 0, 0);
                st[kt] = z;
            }

            // ---- mask + scale ----
            float sv[4][4];
            float tm = -1.0e30f;
            #pragma unroll
            for (int kt = 0; kt < 4; ++kt)
                #pragma unroll
                for (int reg = 0; reg < 4; ++reg) {
                    const int c = kt * 16 + quad * 4 + reg;
                    const int j = gather ? (c << 6) : (tt * 64 + c);
                    const bool valid = gather ? ((c < 32) && (abs(qi - j) > WIN))
                                              : (abs(qi - j) <= WIN);
                    sv[kt][reg] = valid ? st[kt][reg] * 0.125f : -1.0e30f;
                    tm = fmaxf(tm, sv[kt][reg]);
                }

            // ---- online softmax (reduce over quads) ----
            tm = fmaxf(tm, __shfl_xor(tm, 16));
            tm = fmaxf(tm, __shfl_xor(tm, 32));
            const float mn = fmaxf(mq, tm);
            const float alpha = __expf(mq - mn);
            float p[4][4];
            float ts = 0.f;
            #pragma unroll
            for (int kt = 0; kt < 4; ++kt)
                #pragma unroll
                for (int reg = 0; reg < 4; ++reg) {
                    p[kt][reg] = __expf(sv[kt][reg] - mn);
                    ts += p[kt][reg];
                }
            ts += __shfl_xor(ts, 16);
            ts += __shfl_xor(ts, 32);
            lq = lq * alpha + ts;
            mq = mn;

            // ---- P -> LDS (wave-private rows) ----
            #pragma unroll
            for (int kt = 0; kt < 4; ++kt) {
                ushort4 pkt;
                pkt.x = bf16b(p[kt][0]); pkt.y = bf16b(p[kt][1]);
                pkt.z = bf16b(p[kt][2]); pkt.w = bf16b(p[kt][3]);
                *(ushort4*)&Ps[(w * 16 + l15) * 72 + kt * 16 + quad * 4] = pkt;
            }
            #pragma unroll
            for (int jt = 0; jt < 4; ++jt) {
                Oacc[jt][0] *= alpha; Oacc[jt][1] *= alpha;
                Oacc[jt][2] *= alpha; Oacc[jt][3] *= alpha;
            }

            // ---- O^T += V^T @ P^T ----
            short8 bP0 = *(const short8*)&Ps[(w * 16 + l15) * 72 + quad * 8];
            short8 bP1 = *(const short8*)&Ps[(w * 16 + l15) * 72 + 32 + quad * 8];
            #pragma unroll
            for (int jt = 0; jt < 4; ++jt) {
                short8 aV0 = *(const short8*)&Vt[(jt * 16 + l15) * 72 + quad * 8];
                short8 aV1 = *(const short8*)&Vt[(jt * 16 + l15) * 72 + 32 + quad * 8];
                Oacc[jt] = __builtin_amdgcn_mfma_f32_16x16x32_bf16(aV0, bP0, Oacc[jt], 0, 0, 0);
                Oacc[jt] = __builtin_amdgcn_mfma_f32_16x16x32_bf16(aV1, bP1, Oacc[jt], 0, 0, 0);
            }

            if (hasnext) {
                __syncthreads();               // all waves done reading tile tt
                commit((tt + 1) == t1 + 1);    // publish tile tt+1
                __syncthreads();
            }
        }

        // ---- epilogue ----
        if (!(w == 0 && l15 == 0)) {   // skip global rows (qi % 64 == 0)
            const float inv = 1.0f / lq;
            #pragma unroll
            for (int jt = 0; jt < 4; ++jt) {
                ushort4 o;
                o.x = bf16b(Oacc[jt][0] * inv);
                o.y = bf16b(Oacc[jt][1] * inv);
                o.z = bf16b(Oacc[jt][2] * inv);
                o.w = bf16b(Oacc[jt][3] * inv);
                *(ushort4*)&aout16[(size_t)qi * HID + h * HD + jt * 16 + quad * 4] = o;
            }
        }
    } else {
        // ----------------- global-row path (MFMA flash-decoding) -----------
        const int gh = blockIdx.x - 32;   // 0 or 1
        // wave-private regions: Ks [32][72], Vt [64][32], Ps [16][32]
        ushort_t* Ksw = (ushort_t*)(smem + w * 9728);
        ushort_t* Vtw = (ushort_t*)(smem + w * 9728 + 4608);
        ushort_t* Psw = (ushort_t*)(smem + w * 9728 + 8704);

        // Q fragments direct from global (query q = gh*16 + l15, row q*64)
        const size_t qrow = (size_t)((gh * 16 + l15) * 64) * (3 * HID) + h * HD;
        short8 bQ0 = *(const short8*)&qkv16[qrow + quad * 8];
        short8 bQ1 = *(const short8*)&qkv16[qrow + 32 + quad * 8];

        float mq = -1.0e30f, lq = 0.f;
        f32x4 Oacc[4];
        #pragma unroll
        for (int jt = 0; jt < 4; ++jt) Oacc[jt] = (f32x4){0.f, 0.f, 0.f, 0.f};

        for (int s = 0; s < 16; ++s) {
            const int kb = w * 512 + s * 32;   // base key row of this tile
            // ---- stage K (32 rows x 64 dims) ----
            #pragma unroll
            for (int u = 0; u < 4; ++u) {
                const int unit = lane + u * 64;
                const int row = unit >> 3, c8 = unit & 7;
                *(uint4*)&Ksw[row * 72 + c8 * 8] =
                    *(const uint4*)&qkv16[(size_t)(kb + row) * (3 * HID) + HID + h * HD + c8 * 8];
            }
            // ---- stage V^T (64 dims x 32 keys) via key pairs ----
            #pragma unroll
            for (int u = 0; u < 4; ++u) {
                const int unit = lane + u * 64;
                const int kp = unit >> 4, dc = unit & 15;
                const size_t b0 = (size_t)(kb + 2 * kp) * (3 * HID) + 2 * HID + h * HD + dc * 4;
                const size_t b1 = b0 + 3 * HID;
                uint2 va = *(const uint2*)&qkv16[b0];
                uint2 vb = *(const uint2*)&qkv16[b1];
                unsigned int w0 = (va.x & 0xFFFFu) | (vb.x << 16);
                unsigned int w1 = (va.x >> 16)     | (vb.x & 0xFFFF0000u);
                unsigned int w2 = (va.y & 0xFFFFu) | (vb.y << 16);
                unsigned int w3 = (va.y >> 16)     | (vb.y & 0xFFFF0000u);
                *(unsigned int*)&Vtw[(dc * 4 + 0) * 32 + 2 * kp] = w0;
                *(unsigned int*)&Vtw[(dc * 4 + 1) * 32 + 2 * kp] = w1;
                *(unsigned int*)&Vtw[(dc * 4 + 2) * 32 + 2 * kp] = w2;
                *(unsigned int*)&Vtw[(dc * 4 + 3) * 32 + 2 * kp] = w3;
            }

            // ---- S^T = K @ Q^T : 2 key-subtiles of 16 ----
            f32x4 st[2];
            #pragma unroll
            for (int kt = 0; kt < 2; ++kt) {
                short8 aK0 = *(const short8*)&Ksw[(kt * 16 + l15) * 72 + quad * 8];
                short8 aK1 = *(const short8*)&Ksw[(kt * 16 + l15) * 72 + 32 + quad * 8];
                f32x4 z = (f32x4){0.f, 0.f, 0.f, 0.f};
                z = __builtin_amdgcn_mfma_f32_16x16x32_bf16(aK0, bQ0, z, 0, 0, 0);
                z = __builtin_amdgcn_mfma_f32_16x16x32_bf16(aK1, bQ1, z, 0, 0, 0);
                st[kt] = z;
            }

            // ---- online softmax over 32 keys (no mask: global rows) ----
            float sv[2][4];
            float tm = -1.0e30f;
            #pragma unroll
            for (int kt = 0; kt < 2; ++kt)
                #pragma unroll
                for (int reg = 0; reg < 4; ++reg) {
                    sv[kt][reg] = st[kt][reg] * 0.125f;
                    tm = fmaxf(tm, sv[kt][reg]);
                }
            tm = fmaxf(tm, __shfl_xor(tm, 16));
            tm = fmaxf(tm, __shfl_xor(tm, 32));
            const float mn = fmaxf(mq, tm);
            const float alpha = __expf(mq - mn);
            float p[2][4];
            float ts = 0.f;
            #pragma unroll
            for (int kt = 0; kt < 2; ++kt)
                #pragma unroll
                for (int reg = 0; reg < 4; ++reg) {
                    p[kt][reg] = __expf(sv[kt][reg] - mn);
                    ts += p[kt][reg];
                }
            ts += __shfl_xor(ts, 16);
            ts += __shfl_xor(ts, 32);
            lq = lq * alpha + ts;
            mq = mn;

            // ---- P -> LDS ----
            #pragma unroll
            for (int kt = 0; kt < 2; ++kt) {
                ushort4 pkt;
                pkt.x = bf16b(p[kt][0]); pkt.y = bf16b(p[kt][1]);
                pkt.z = bf16b(p[kt][2]); pkt.w = bf16b(p[kt][3]);
                *(ushort4*)&Psw[l15 * 32 + kt * 16 + quad * 4] = pkt;
            }
            #pragma unroll
            for (int jt = 0; jt < 4; ++jt) {
                Oacc[jt][0] *= alpha; Oacc[jt][1] *= alpha;
                Oacc[jt][2] *= alpha; Oacc[jt][3] *= alpha;
            }

            // ---- O^T += V^T @ P^T (K-dim = 32 keys, 1 mfma per jt) ----
            short8 bP = *(const short8*)&Psw[l15 * 32 + quad * 8];
            #pragma unroll
            for (int jt = 0; jt < 4; ++jt) {
                short8 aV = *(const short8*)&Vtw[(jt * 16 + l15) * 32 + quad * 8];
                Oacc[jt] = __builtin_amdgcn_mfma_f32_16x16x32_bf16(aV, bP, Oacc[jt], 0, 0, 0);
            }
        }

        // ---- merge the 4 waves' partials (m,l,O) via LDS ----
        __syncthreads();
        float* Om = (float*)smem;              // [4][16][64]
        float* Ml = (float*)(smem + 16384);    // [4][16]
        float* Ll = (float*)(smem + 16640);    // [4][16]
        #pragma unroll
        for (int jt = 0; jt < 4; ++jt)
            #pragma unroll
            for (int reg = 0; reg < 4; ++reg)
                Om[(w * 16 + l15) * 64 + jt * 16 + quad * 4 + reg] = Oacc[jt][reg];
        if (quad == 0) { Ml[w * 16 + l15] = mq; Ll[w * 16 + l15] = lq; }
        __syncthreads();

        const int d = tid & 63;
        #pragma unroll
        for (int k = 0; k < 4; ++k) {
            const int q = (tid >> 6) * 4 + k;
            float m0 = Ml[q], m1 = Ml[16 + q], m2 = Ml[32 + q], m3 = Ml[48 + q];
            float mM = fmaxf(fmaxf(m0, m1), fmaxf(m2, m3));
            float e0 = __expf(m0 - mM), e1 = __expf(m1 - mM);
            float e2 = __expf(m2 - mM), e3 = __expf(m3 - mM);
            float l = e0 * Ll[q] + e1 * Ll[16 + q] + e2 * Ll[32 + q] + e3 * Ll[48 + q];
            float o = e0 * Om[(q) * 64 + d]        + e1 * Om[(16 + q) * 64 + d]
                    + e2 * Om[(32 + q) * 64 + d]   + e3 * Om[(48 + q) * 64 + d];
            const int i = (gh * 16 + q) * 64;
            aout16[(size_t)i * HID + h * HD + d] = bf16b(o / l);
        }
    }
}

extern "C" void kernel_launch(void* const* d_in, const int* in_sizes, int n_in,
                              void* d_out, int out_size, void* d_ws, size_t ws_size,
                              hipStream_t stream) {
    const float* x    = (const float*)d_in[0];   // [2048,1024] fp32
    const float* Wqkv = (const float*)d_in[1];   // [3072,1024] fp32
    const float* Wout = (const float*)d_in[2];   // [1024,1024] fp32
    float* out = (float*)d_out;                  // [2048,1024] fp32

    unsigned short* x16    = (unsigned short*)d_ws;                 // 2048*1024
    unsigned short* wq16   = x16  + (size_t)SEQ * HID;              // 3072*1024
    unsigned short* wo16   = wq16 + (size_t)3 * HID * HID;          // 1024*1024
    unsigned short* qkv16  = wo16 + (size_t)HID * HID;              // 2048*3072
    unsigned short* aout16 = qkv16 + (size_t)SEQ * 3 * HID;         // 2048*1024

    // 0) fp32 -> bf16 conversions
    cvt_bf16<<<dim3(1024), 256, 0, stream>>>(
        (const float4*)x, (const float4*)Wqkv, (const float4*)Wout,
        (ushort4*)x16, (ushort4*)wq16, (ushort4*)wo16);

    // 1) qkv16 = x16 @ wq16^T  (bf16 out)
    gemm_bt16<128, unsigned short><<<dim3(3 * HID / 128, SEQ / 128), 256, 0, stream>>>(
        x16, wq16, qkv16, SEQ, 3 * HID, HID);

    // 2) fused banded (prefetch) + global (MFMA flash-decoding) attention
    attn_fused<<<dim3(34, NH), 256, 0, stream>>>(qkv16, aout16);

    // 3) out = aout16 @ wo16^T  (fp32 out), BN=64 -> 256 blocks
    gemm_bt16<64, float><<<dim3(HID / 64, SEQ / 128), 256, 0, stream>>>(
        aout16, wo16, out, SEQ, HID, HID);
}

// Round 10
// 151.689 us; speedup vs baseline: 16.5619x; 1.0487x over previous
//
#include <hip/hip_runtime.h>
#include <hip/hip_bf16.h>
#include <math.h>

// Problem constants (B=1)
#define SEQ   2048
#define HID   1024
#define NH    16
#define HD    64
#define WIN   128
#define GSTR  64

typedef __attribute__((ext_vector_type(8))) short short8;   // 8 bf16 = 4 VGPRs
typedef __attribute__((ext_vector_type(4))) float f32x4;    // MFMA C/D
typedef unsigned short ushort_t;

// RNE fp32 -> bf16 bits (finite inputs)
__device__ inline unsigned short bf16b(float f) {
    union { float f; unsigned int u; } v; v.f = f;
    return (unsigned short)((v.u + 0x7FFFu + ((v.u >> 16) & 1u)) >> 16);
}
// bf16 (low/high ushort of a uint) -> fp32
__device__ inline float blo(unsigned int u) {
    union { unsigned int i; float f; } v; v.i = u << 16; return v.f;
}
__device__ inline float bhi(unsigned int u) {
    union { unsigned int i; float f; } v; v.i = u & 0xFFFF0000u; return v.f;
}

#define GLOAD_LDS16(gp, lp)                                                    \
    __builtin_amdgcn_global_load_lds(                                          \
        (const __attribute__((address_space(1))) unsigned int*)(gp),           \
        (__attribute__((address_space(3))) unsigned int*)(lp), 16, 0, 0)

// ---------------------------------------------------------------------------
// fp32 -> bf16 pre-convert of x, Wqkv, Wout
// ---------------------------------------------------------------------------
__global__ __launch_bounds__(256) void cvt_bf16(const float4* __restrict__ x,
                                                const float4* __restrict__ wq,
                                                const float4* __restrict__ wo,
                                                ushort4* __restrict__ x16,
                                                ushort4* __restrict__ wq16,
                                                ushort4* __restrict__ wo16) {
    for (int idx = blockIdx.x * 256 + threadIdx.x; idx < 1572864;
         idx += gridDim.x * 256) {
        const float4* src; ushort4* dst; int off;
        if (idx < 524288)       { src = x;  dst = x16;  off = idx; }
        else if (idx < 1310720) { src = wq; dst = wq16; off = idx - 524288; }
        else                    { src = wo; dst = wo16; off = idx - 1310720; }
        float4 v = src[off];
        ushort4 o;
        o.x = bf16b(v.x); o.y = bf16b(v.y); o.z = bf16b(v.z); o.w = bf16b(v.w);
        dst[off] = o;
    }
}

// ---------------------------------------------------------------------------
// m97-style MFMA GEMM: C[M,N] = A[M,K] @ B[N,K]^T, bf16 in, fp32 acc.
// Tile BM x BN (each 64 or 128), BK=32, 256 threads (4 waves, 2x2 wave grid).
// Small tiles -> more blocks: grid-starved shapes need >= 2-3 blocks/CU for
// the implicit wave-level overlap that hides the barrier drain (m114).
// ---------------------------------------------------------------------------
template <int BM, int BN, typename OT>
__global__ __launch_bounds__(256) void gemm_bt16(const unsigned short* __restrict__ A,
                                                 const unsigned short* __restrict__ B,
                                                 OT* __restrict__ C,
                                                 int M, int N, int K) {
    constexpr int MI = BM / 32;
    constexpr int NJ = BN / 32;
    __shared__ unsigned short As[BM * 32];
    __shared__ unsigned short Bs[BN * 32];

    const int tid  = threadIdx.x;
    const int wave = tid >> 6;
    const int lane = tid & 63;
    const int quad = lane >> 4;
    const int l15  = lane & 15;
    const int bm = blockIdx.y * BM;
    const int bn = blockIdx.x * BN;
    const int wm = (wave & 1) * (BM / 2);
    const int wn = (wave >> 1) * (BN / 2);
    const int srow = lane >> 2;
    const int scol = (lane & 3) * 8;

    f32x4 acc[MI][NJ];
    #pragma unroll
    for (int i = 0; i < MI; ++i)
        #pragma unroll
        for (int j = 0; j < NJ; ++j)
            acc[i][j] = (f32x4){0.f, 0.f, 0.f, 0.f};

    for (int k0 = 0; k0 < K; k0 += 32) {
        #pragma unroll
        for (int t = 0; t < BM / 64; ++t) {
            const int row = wave * (BM / 4) + t * 16 + srow;
            GLOAD_LDS16(A + (size_t)(bm + row) * K + k0 + scol,
                        &As[(size_t)row * 32 + scol]);
        }
        #pragma unroll
        for (int t = 0; t < BN / 64; ++t) {
            const int row = wave * (BN / 4) + t * 16 + srow;
            GLOAD_LDS16(B + (size_t)(bn + row) * K + k0 + scol,
                        &Bs[(size_t)row * 32 + scol]);
        }
        __syncthreads();

        short8 a[MI], b[NJ];
        #pragma unroll
        for (int im = 0; im < MI; ++im)
            a[im] = *(const short8*)&As[(wm + im * 16 + l15) * 32 + quad * 8];
        #pragma unroll
        for (int jn = 0; jn < NJ; ++jn)
            b[jn] = *(const short8*)&Bs[(wn + jn * 16 + l15) * 32 + quad * 8];

        #pragma unroll
        for (int im = 0; im < MI; ++im)
            #pragma unroll
            for (int jn = 0; jn < NJ; ++jn)
                acc[im][jn] = __builtin_amdgcn_mfma_f32_16x16x32_bf16(
                    a[im], b[jn], acc[im][jn], 0, 0, 0);
        __syncthreads();
    }

    #pragma unroll
    for (int im = 0; im < MI; ++im)
        #pragma unroll
        for (int jn = 0; jn < NJ; ++jn)
            #pragma unroll
            for (int reg = 0; reg < 4; ++reg) {
                const int r = bm + wm + im * 16 + quad * 4 + reg;
                const int c = bn + wn + jn * 16 + l15;
                float v = acc[im][jn][reg];
                if constexpr (sizeof(OT) == 2)
                    C[(size_t)r * N + c] = (OT)bf16b(v);
                else
                    C[(size_t)r * N + c] = (OT)v;
            }
}

// ---------------------------------------------------------------------------
// Fused attention (unchanged from R9). qkv16: [SEQ][3*HID] bf16.
// ---------------------------------------------------------------------------
__global__ __launch_bounds__(256) void attn_fused(const unsigned short* __restrict__ qkv16,
                                                  unsigned short* __restrict__ aout16) {
    __shared__ __align__(16) unsigned char smem[38912];
    const int tid = threadIdx.x;
    const int h = blockIdx.y;
    const int w    = tid >> 6;
    const int lane = tid & 63;
    const int quad = lane >> 4;
    const int l15  = lane & 15;

    if (blockIdx.x < 32) {
        // ----------------- banded path (S^T MFMA + prefetch) -----------------
        ushort_t* Qs = (ushort_t*)smem;              // [64][72] bf16, 9216 B
        ushort_t* Ks = (ushort_t*)(smem + 9216);     // [64][72]
        ushort_t* Vt = (ushort_t*)(smem + 18432);    // [64][72]  Vt[d][key]
        ushort_t* Ps = (ushort_t*)(smem + 27648);    // [64][72]  Ps[q][key]

        const int bq = blockIdx.x;
        const int q0 = bq * 64;
        const int qi = q0 + w * 16 + l15;   // this lane's query

        for (int f = tid; f < 512; f += 256) {
            int row = f >> 3, c8 = f & 7;
            *(uint4*)&Qs[row * 72 + c8 * 8] =
                *(const uint4*)&qkv16[(size_t)(q0 + row) * (3 * HID) + h * HD + c8 * 8];
        }

        float mq = -1.0e30f, lq = 0.f;
        f32x4 Oacc[4];
        #pragma unroll
        for (int jt = 0; jt < 4; ++jt) Oacc[jt] = (f32x4){0.f, 0.f, 0.f, 0.f};

        const int t0 = max(bq - 2, 0);
        const int t1 = min(bq + 2, SEQ / 64 - 1);

        uint4 pk[2];
        uint2 pva[2], pvb[2];

        auto prefetch = [&](int tt2, bool g2) {
            const int nf = g2 ? 256 : 512;
            #pragma unroll
            for (int u = 0; u < 2; ++u) {
                const int f = tid + u * 256;
                if (f < nf) {
                    const int row = f >> 3, c8 = f & 7;
                    const size_t gb = (size_t)(g2 ? (row << 6) : (tt2 * 64 + row))
                                          * (3 * HID) + HID + h * HD + c8 * 8;
                    pk[u] = *(const uint4*)&qkv16[gb];
                    const int kp = f >> 4, dc = f & 15;
                    const int k0i = 2 * kp, k1i = 2 * kp + 1;
                    const size_t b0 = (size_t)(g2 ? (k0i << 6) : (tt2 * 64 + k0i))
                                          * (3 * HID) + 2 * HID + h * HD + dc * 4;
                    const size_t b1 = (size_t)(g2 ? (k1i << 6) : (tt2 * 64 + k1i))
                                          * (3 * HID) + 2 * HID + h * HD + dc * 4;
                    pva[u] = *(const uint2*)&qkv16[b0];
                    pvb[u] = *(const uint2*)&qkv16[b1];
                }
            }
        };
        auto commit = [&](bool g2) {
            const int nf = g2 ? 256 : 512;
            #pragma unroll
            for (int u = 0; u < 2; ++u) {
                const int f = tid + u * 256;
                if (f < nf) {
                    const int row = f >> 3, c8 = f & 7;
                    *(uint4*)&Ks[row * 72 + c8 * 8] = pk[u];
                    const int kp = f >> 4, dc = f & 15;
                    uint2 va = pva[u], vb = pvb[u];
                    unsigned int w0 = (va.x & 0xFFFFu) | (vb.x << 16);
                    unsigned int w1 = (va.x >> 16)     | (vb.x & 0xFFFF0000u);
                    unsigned int w2 = (va.y & 0xFFFFu) | (vb.y << 16);
                    unsigned int w3 = (va.y >> 16)     | (vb.y & 0xFFFF0000u);
                    *(unsigned int*)&Vt[(dc * 4 + 0) * 72 + 2 * kp] = w0;
                    *(unsigned int*)&Vt[(dc * 4 + 1) * 72 + 2 * kp] = w1;
                    *(unsigned int*)&Vt[(dc * 4 + 2) * 72 + 2 * kp] = w2;
                    *(unsigned int*)&Vt[(dc * 4 + 3) * 72 + 2 * kp] = w3;
                }
            }
        };

        prefetch(t0, false);
        commit(false);
        __syncthreads();

        for (int tt = t0; tt <= t1 + 1; ++tt) {
            const bool gather = (tt == t1 + 1);
            const bool hasnext = (tt < t1 + 1);
            if (hasnext) prefetch(tt + 1, (tt + 1) == t1 + 1);

            short8 bQ0 = *(const short8*)&Qs[(w * 16 + l15) * 72 + quad * 8];
            short8 bQ1 = *(const short8*)&Qs[(w * 16 + l15) * 72 + 32 + quad * 8];
            f32x4 st[4];
            #pragma unroll
            for (int kt = 0; kt < 4; ++kt) {
                short8 aK0 = *(const short8*)&Ks[(kt * 16 + l15) * 72 + quad * 8];
                short8 aK1 = *(const short8*)&Ks[(kt * 16 + l15) * 72 + 32 + quad * 8];
                f32x4 z = (f32x4){0.f, 0.f, 0.f, 0.f};
                z = __builtin_amdgcn_mfma_f32_16x16x32_bf16(aK0, bQ0, z, 0, 0, 0);
                z = __builtin_amdgcn_mfma_f32_16x16x32_bf16(aK1, bQ1, z, 0, 0, 0);
                st[kt] = z;
            }

            float sv[4][4];
            float tm = -1.0e30f;
            #pragma unroll
            for (int kt = 0; kt < 4; ++kt)
                #pragma unroll
                for (int reg = 0; reg < 4; ++reg) {
                    const int c = kt * 16 + quad * 4 + reg;
                    const int j = gather ? (c << 6) : (tt * 64 + c);
                    const bool valid = gather ? ((c < 32) && (abs(qi - j) > WIN))
                                              : (abs(qi - j) <= WIN);
                    sv[kt][reg] = valid ? st[kt][reg] * 0.125f : -1.0e30f;
                    tm = fmaxf(tm, sv[kt][reg]);
                }

            tm = fmaxf(tm, __shfl_xor(tm, 16));
            tm = fmaxf(tm, __shfl_xor(tm, 32));
            const float mn = fmaxf(mq, tm);
            const float alpha = __expf(mq - mn);
            float p[4][4];
            float ts = 0.f;
            #pragma unroll
            for (int kt = 0; kt < 4; ++kt)
                #pragma unroll
                for (int reg = 0; reg < 4; ++reg) {
                    p[kt][reg] = __expf(sv[kt][reg] - mn);
                    ts += p[kt][reg];
                }
            ts += __shfl_xor(ts, 16);
            ts += __shfl_xor(ts, 32);
            lq = lq * alpha + ts;
            mq = mn;

            #pragma unroll
            for (int kt = 0; kt < 4; ++kt) {
                ushort4 pkt;
                pkt.x = bf16b(p[kt][0]); pkt.y = bf16b(p[kt][1]);
                pkt.z = bf16b(p[kt][2]); pkt.w = bf16b(p[kt][3]);
                *(ushort4*)&Ps[(w * 16 + l15) * 72 + kt * 16 + quad * 4] = pkt;
            }
            #pragma unroll
            for (int jt = 0; jt < 4; ++jt) {
                Oacc[jt][0] *= alpha; Oacc[jt][1] *= alpha;
                Oacc[jt][2] *= alpha; Oacc[jt][3] *= alpha;
            }

            short8 bP0 = *(const short8*)&Ps[(w * 16 + l15) * 72 + quad * 8];
            short8 bP1 = *(const short8*)&Ps[(w * 16 + l15) * 72 + 32 + quad * 8];
            #pragma unroll
            for (int jt = 0; jt < 4; ++jt) {
                short8 aV0 = *(const short8*)&Vt[(jt * 16 + l15) * 72 + quad * 8];
                short8 aV1 = *(const short8*)&Vt[(jt * 16 + l15) * 72 + 32 + quad * 8];
                Oacc[jt] = __builtin_amdgcn_mfma_f32_16x16x32_bf16(aV0, bP0, Oacc[jt], 0, 0, 0);
                Oacc[jt] = __builtin_amdgcn_mfma_f32_16x16x32_bf16(aV1, bP1, Oacc[jt], 0, 0, 0);
            }

            if (hasnext) {
                __syncthreads();
                commit((tt + 1) == t1 + 1);
                __syncthreads();
            }
        }

        if (!(w == 0 && l15 == 0)) {   // skip global rows (qi % 64 == 0)
            const float inv = 1.0f / lq;
            #pragma unroll
            for (int jt = 0; jt < 4; ++jt) {
                ushort4 o;
                o.x = bf16b(Oacc[jt][0] * inv);
                o.y = bf16b(Oacc[jt][1] * inv);
                o.z = bf16b(Oacc[jt][2] * inv);
                o.w = bf16b(Oacc[jt][3] * inv);
                *(ushort4*)&aout16[(size_t)qi * HID + h * HD + jt * 16 + quad * 4] = o;
            }
        }
    } else {
        // ----------------- global-row path (MFMA flash-decoding) -----------
        const int gh = blockIdx.x - 32;   // 0 or 1
        ushort_t* Ksw = (ushort_t*)(smem + w * 9728);
        ushort_t* Vtw = (ushort_t*)(smem + w * 9728 + 4608);
        ushort_t* Psw = (ushort_t*)(smem + w * 9728 + 8704);

        const size_t qrow = (size_t)((gh * 16 + l15) * 64) * (3 * HID) + h * HD;
        short8 bQ0 = *(const short8*)&qkv16[qrow + quad * 8];
        short8 bQ1 = *(const short8*)&qkv16[qrow + 32 + quad * 8];

        float mq = -1.0e30f, lq = 0.f;
        f32x4 Oacc[4];
        #pragma unroll
        for (int jt = 0; jt < 4; ++jt) Oacc[jt] = (f32x4){0.f, 0.f, 0.f, 0.f};

        for (int s = 0; s < 16; ++s) {
            const int kb = w * 512 + s * 32;
            #pragma unroll
            for (int u = 0; u < 4; ++u) {
                const int unit = lane + u * 64;
                const int row = unit >> 3, c8 = unit & 7;
                *(uint4*)&Ksw[row * 72 + c8 * 8] =
                    *(const uint4*)&qkv16[(size_t)(kb + row) * (3 * HID) + HID + h * HD + c8 * 8];
            }
            #pragma unroll
            for (int u = 0; u < 4; ++u) {
                const int unit = lane + u * 64;
                const int kp = unit >> 4, dc = unit & 15;
                const size_t b0 = (size_t)(kb + 2 * kp) * (3 * HID) + 2 * HID + h * HD + dc * 4;
                const size_t b1 = b0 + 3 * HID;
                uint2 va = *(const uint2*)&qkv16[b0];
                uint2 vb = *(const uint2*)&qkv16[b1];
                unsigned int w0 = (va.x & 0xFFFFu) | (vb.x << 16);
                unsigned int w1 = (va.x >> 16)     | (vb.x & 0xFFFF0000u);
                unsigned int w2 = (va.y & 0xFFFFu) | (vb.y << 16);
                unsigned int w3 = (va.y >> 16)     | (vb.y & 0xFFFF0000u);
                *(unsigned int*)&Vtw[(dc * 4 + 0) * 32 + 2 * kp] = w0;
                *(unsigned int*)&Vtw[(dc * 4 + 1) * 32 + 2 * kp] = w1;
                *(unsigned int*)&Vtw[(dc * 4 + 2) * 32 + 2 * kp] = w2;
                *(unsigned int*)&Vtw[(dc * 4 + 3) * 32 + 2 * kp] = w3;
            }

            f32x4 st[2];
            #pragma unroll
            for (int kt = 0; kt < 2; ++kt) {
                short8 aK0 = *(const short8*)&Ksw[(kt * 16 + l15) * 72 + quad * 8];
                short8 aK1 = *(const short8*)&Ksw[(kt * 16 + l15) * 72 + 32 + quad * 8];
                f32x4 z = (f32x4){0.f, 0.f, 0.f, 0.f};
                z = __builtin_amdgcn_mfma_f32_16x16x32_bf16(aK0, bQ0, z, 0, 0, 0);
                z = __builtin_amdgcn_mfma_f32_16x16x32_bf16(aK1, bQ1, z, 0, 0, 0);
                st[kt] = z;
            }

            float sv[2][4];
            float tm = -1.0e30f;
            #pragma unroll
            for (int kt = 0; kt < 2; ++kt)
                #pragma unroll
                for (int reg = 0; reg < 4; ++reg) {
                    sv[kt][reg] = st[kt][reg] * 0.125f;
                    tm = fmaxf(tm, sv[kt][reg]);
                }
            tm = fmaxf(tm, __shfl_xor(tm, 16));
            tm = fmaxf(tm, __shfl_xor(tm, 32));
            const float mn = fmaxf(mq, tm);
            const float alpha = __expf(mq - mn);
            float p[2][4];
            float ts = 0.f;
            #pragma unroll
            for (int kt = 0; kt < 2; ++kt)
                #pragma unroll
                for (int reg = 0; reg < 4; ++reg) {
                    p[kt][reg] = __expf(sv[kt][reg] - mn);
                    ts += p[kt][reg];
                }
            ts += __shfl_xor(ts, 16);
            ts += __shfl_xor(ts, 32);
            lq = lq * alpha + ts;
            mq = mn;

            #pragma unroll
            for (int kt = 0; kt < 2; ++kt) {
                ushort4 pkt;
                pkt.x = bf16b(p[kt][0]); pkt.y = bf16b(p[kt][1]);
                pkt.z = bf16b(p[kt][2]); pkt.w = bf16b(p[kt][3]);
                *(ushort4*)&Psw[l15 * 32 + kt * 16 + quad * 4] = pkt;
            }
            #pragma unroll
            for (int jt = 0; jt < 4; ++jt) {
                Oacc[jt][0] *= alpha; Oacc[jt][1] *= alpha;
                Oacc[jt][2] *= alpha; Oacc[jt][3] *= alpha;
            }

            short8 bP = *(const short8*)&Psw[l15 * 32 + quad * 8];
            #pragma unroll
            for (int jt = 0; jt < 4; ++jt) {
                short8 aV = *(const short8*)&Vtw[(jt * 16 + l15) * 32 + quad * 8];
                Oacc[jt] = __builtin_amdgcn_mfma_f32_16x16x32_bf16(aV, bP, Oacc[jt], 0, 0, 0);
            }
        }

        __syncthreads();
        float* Om = (float*)smem;              // [4][16][64]
        float* Ml = (float*)(smem + 16384);    // [4][16]
        float* Ll = (float*)(smem + 16640);    // [4][16]
        #pragma unroll
        for (int jt = 0; jt < 4; ++jt)
            #pragma unroll
            for (int reg = 0; reg < 4; ++reg)
                Om[(w * 16 + l15) * 64 + jt * 16 + quad * 4 + reg] = Oacc[jt][reg];
        if (quad == 0) { Ml[w * 16 + l15] = mq; Ll[w * 16 + l15] = lq; }
        __syncthreads();

        const int d = tid & 63;
        #pragma unroll
        for (int k = 0; k < 4; ++k) {
            const int q = (tid >> 6) * 4 + k;
            float m0 = Ml[q], m1 = Ml[16 + q], m2 = Ml[32 + q], m3 = Ml[48 + q];
            float mM = fmaxf(fmaxf(m0, m1), fmaxf(m2, m3));
            float e0 = __expf(m0 - mM), e1 = __expf(m1 - mM);
            float e2 = __expf(m2 - mM), e3 = __expf(m3 - mM);
            float l = e0 * Ll[q] + e1 * Ll[16 + q] + e2 * Ll[32 + q] + e3 * Ll[48 + q];
            float o = e0 * Om[(q) * 64 + d]        + e1 * Om[(16 + q) * 64 + d]
                    + e2 * Om[(32 + q) * 64 + d]   + e3 * Om[(48 + q) * 64 + d];
            const int i = (gh * 16 + q) * 64;
            aout16[(size_t)i * HID + h * HD + d] = bf16b(o / l);
        }
    }
}

extern "C" void kernel_launch(void* const* d_in, const int* in_sizes, int n_in,
                              void* d_out, int out_size, void* d_ws, size_t ws_size,
                              hipStream_t stream) {
    const float* x    = (const float*)d_in[0];   // [2048,1024] fp32
    const float* Wqkv = (const float*)d_in[1];   // [3072,1024] fp32
    const float* Wout = (const float*)d_in[2];   // [1024,1024] fp32
    float* out = (float*)d_out;                  // [2048,1024] fp32

    unsigned short* x16    = (unsigned short*)d_ws;                 // 2048*1024
    unsigned short* wq16   = x16  + (size_t)SEQ * HID;              // 3072*1024
    unsigned short* wo16   = wq16 + (size_t)3 * HID * HID;          // 1024*1024
    unsigned short* qkv16  = wo16 + (size_t)HID * HID;              // 2048*3072
    unsigned short* aout16 = qkv16 + (size_t)SEQ * 3 * HID;         // 2048*1024

    // 0) fp32 -> bf16 conversions
    cvt_bf16<<<dim3(1024), 256, 0, stream>>>(
        (const float4*)x, (const float4*)Wqkv, (const float4*)Wout,
        (ushort4*)x16, (ushort4*)wq16, (ushort4*)wo16);

    // 1) qkv16 = x16 @ wq16^T  (bf16 out): 64x128 tile -> 768 blocks (3/CU)
    gemm_bt16<64, 128, unsigned short><<<dim3(3 * HID / 128, SEQ / 64), 256, 0, stream>>>(
        x16, wq16, qkv16, SEQ, 3 * HID, HID);

    // 2) fused banded (prefetch) + global (MFMA flash-decoding) attention
    attn_fused<<<dim3(34, NH), 256, 0, stream>>>(qkv16, aout16);

    // 3) out = aout16 @ wo16^T  (fp32 out): 64x64 tile -> 512 blocks (2/CU)
    gemm_bt16<64, 64, float><<<dim3(HID / 64, SEQ / 64), 256, 0, stream>>>(
        aout16, wo16, out, SEQ, HID, HID);
}